// Round 5
// baseline (450.113 us; speedup 1.0000x reference)
//
#include <hip/hip_runtime.h>
#include <hip/hip_bf16.h>
#include <math.h>

// ---------------------------------------------------------------------------
// GCN forward on MI355X (fp32 end-to-end; no fp32 MFMA on CDNA4).
// Pipeline:
//   deg -> scan -> CSR fill (by dst, self-loops included)
//   M = W_enc @ Wc0, bfold = b_enc @ Wc0   (encoder folded into layer-0 GEMM)
//   l0: hw = (x @ M + bfold) * dinv[row]          [k_gemm<64>]
//       h  = gather-sum(hw[col]) * dinv + bc0     [k_agg, BN stats fused]
//   l1: hw = (bnrelu(h) @ Wc1) * dinv[row]        [k_gemm<128>, BN fused in]
//       h  = gather-sum(hw[col]) * dinv + bc1     [k_agg, BN stats fused]
//   pool (BN+ReLU fused) -> MLP head -> sigmoid
// Lessons applied:
//   R2: full K-unroll spills (VGPR 256, 247MB scratch) -> #pragma unroll 1.
//   R3: k_agg is latency-bound (VALUBusy 6%, occ 32%) -> 2048 blocks +
//       edge-loop unroll x4 for 8x outstanding gathers.
//   R4: no data (GPU acquisition timeout) -> resubmitted unchanged.
// ---------------------------------------------------------------------------

__global__ __launch_bounds__(256) void k_init(int* __restrict__ deg,
                                              float* __restrict__ pooled,
                                              float* __restrict__ bnstat,
                                              int N) {
  int i = blockIdx.x * 256 + threadIdx.x;
  if (i < N) deg[i] = 1;           // self-loop
  if (i < 64 * 128) pooled[i] = 0.f;
  if (i < 512) bnstat[i] = 0.f;    // sum/sumsq for both layers
}

__global__ __launch_bounds__(256) void k_deg(const int* __restrict__ ei, int E,
                                             int* __restrict__ deg) {
  int i = blockIdx.x * 256 + threadIdx.x;
  if (i < E) atomicAdd(&deg[ei[E + i]], 1);   // dst row
}

// ---- 3-kernel exclusive scan over deg[N] -> rowptr ----
__global__ __launch_bounds__(256) void k_scan_a(const int* __restrict__ deg, int N,
                                                int* __restrict__ rowptr,
                                                int* __restrict__ blksum) {
  __shared__ int s[256];
  int t = threadIdx.x;
  int i = blockIdx.x * 256 + t;
  int v = (i < N) ? deg[i] : 0;
  s[t] = v;
  __syncthreads();
  for (int off = 1; off < 256; off <<= 1) {
    int x = (t >= off) ? s[t - off] : 0;
    __syncthreads();
    s[t] += x;
    __syncthreads();
  }
  if (i < N) rowptr[i] = s[t] - v;            // exclusive (partial)
  if (t == 255) blksum[blockIdx.x] = s[255];
}

__global__ __launch_bounds__(256) void k_scan_b(int* __restrict__ blksum, int nb) {
  __shared__ int s[256];
  int t = threadIdx.x;
  int v = (t < nb) ? blksum[t] : 0;
  s[t] = v;
  __syncthreads();
  for (int off = 1; off < 256; off <<= 1) {
    int x = (t >= off) ? s[t - off] : 0;
    __syncthreads();
    s[t] += x;
    __syncthreads();
  }
  if (t < nb) blksum[t] = s[t] - v;           // exclusive
}

__global__ __launch_bounds__(256) void k_scan_c(const int* __restrict__ deg, int N,
                                                int total,
                                                const int* __restrict__ blksum,
                                                int* __restrict__ rowptr,
                                                int* __restrict__ cursor,
                                                float* __restrict__ dinv) {
  int i = blockIdx.x * 256 + threadIdx.x;
  if (i < N) {
    int rp = rowptr[i] + blksum[blockIdx.x];
    rowptr[i] = rp;
    cursor[i] = rp;
    dinv[i] = rsqrtf((float)deg[i]);
  } else if (i == N) {
    rowptr[N] = total;
  }
}

__global__ __launch_bounds__(256) void k_fill(const int* __restrict__ ei, int E, int N,
                                              int* __restrict__ cursor,
                                              int* __restrict__ colx) {
  int i = blockIdx.x * 256 + threadIdx.x;
  if (i < E) {
    int s = ei[i];
    int d = ei[E + i];
    int pos = atomicAdd(&cursor[d], 1);
    colx[pos] = s;
  } else if (i < E + N) {
    int j = i - E;
    int pos = atomicAdd(&cursor[j], 1);
    colx[pos] = j;                           // self-loop entry
  }
}

// ---- Fold encoder into layer-0 weights: M = W_enc @ Wc0, bfold = b_enc @ Wc0
__global__ __launch_bounds__(128) void k_fold(const float* __restrict__ W_enc,
                                              const float* __restrict__ b_enc,
                                              const float* __restrict__ Wc0,
                                              float* __restrict__ M,
                                              float* __restrict__ bfold) {
  int n = threadIdx.x;                 // 0..127
  int k = blockIdx.x;                  // 0..64 (64 == bias row)
  const float* arow = (k < 64) ? (W_enc + (size_t)k * 128) : b_enc;
  float acc = 0.f;
  for (int j = 0; j < 128; j++) acc = fmaf(arow[j], Wc0[(size_t)j * 128 + n], acc);
  if (k < 64) M[(size_t)k * 128 + n] = acc;
  else bfold[n] = acc;
}

// ---- GEMM: Y[N][128] = f(X)[N][K] @ W[K][128] (+bias) (*scale[row]) ----
// f = BN(scale/shift)+ReLU applied during X staging when scsh != nullptr.
// block=256 (4 waves), 32 rows/block. W and X tile both in LDS.
// Per k-group(4): 8x ds_read_b128 (X, wave-uniform broadcast -> cheap) +
// 4x ds_read_b64 (W, 2-way = free) + 64 FMA.
template <int K>
__global__ __launch_bounds__(256, 2) void k_gemm(const float* __restrict__ X,
                                                 const float* __restrict__ W,
                                                 const float* __restrict__ bias,
                                                 const float* __restrict__ scale,
                                                 const float* __restrict__ scsh,
                                                 float* __restrict__ Y, int N) {
  __shared__ float Wl[K * 128];
  __shared__ float Xl[32 * K];
  const int K4 = K / 4;

  for (int i = threadIdx.x; i < K * 32; i += 256)   // K*128/4 float4s
    ((float4*)Wl)[i] = ((const float4*)W)[i];

  int rowBlk = blockIdx.x * 32;
  for (int i = threadIdx.x; i < 32 * K4; i += 256) {
    int r = i / K4, c4 = i - r * K4;
    int row = rowBlk + r;
    if (row >= N) row = N - 1;                      // clamp (writes guarded)
    float4 v = ((const float4*)(X + (size_t)row * K))[c4];
    if (scsh) {                                     // fused BN+ReLU of prev layer
      float4 sc = ((const float4*)scsh)[c4];
      float4 sh = ((const float4*)(scsh + 128))[c4];
      v.x = fmaxf(fmaf(v.x, sc.x, sh.x), 0.f);
      v.y = fmaxf(fmaf(v.y, sc.y, sh.y), 0.f);
      v.z = fmaxf(fmaf(v.z, sc.z, sh.z), 0.f);
      v.w = fmaxf(fmaf(v.w, sc.w, sh.w), 0.f);
    }
    ((float4*)Xl)[i] = v;
  }
  __syncthreads();

  int lane = threadIdx.x & 63;
  int wv = threadIdx.x >> 6;
  int c0 = 2 * lane;
  int lr0 = wv * 8;
  int rowBase = rowBlk + lr0;

  float2 bb = make_float2(0.f, 0.f);
  if (bias) bb = *(const float2*)&bias[c0];

  float a0[8], a1[8];
#pragma unroll
  for (int r = 0; r < 8; r++) { a0[r] = bb.x; a1[r] = bb.y; }

#pragma unroll 1
  for (int k = 0; k < K; k += 4) {
    float2 w0 = *(const float2*)&Wl[(k + 0) * 128 + c0];
    float2 w1 = *(const float2*)&Wl[(k + 1) * 128 + c0];
    float2 w2 = *(const float2*)&Wl[(k + 2) * 128 + c0];
    float2 w3 = *(const float2*)&Wl[(k + 3) * 128 + c0];
    float4 xv[8];
#pragma unroll
    for (int r = 0; r < 8; r++)
      xv[r] = *(const float4*)&Xl[(lr0 + r) * K + k];
#pragma unroll
    for (int r = 0; r < 8; r++) {
      a0[r] = fmaf(xv[r].x, w0.x, a0[r]); a1[r] = fmaf(xv[r].x, w0.y, a1[r]);
      a0[r] = fmaf(xv[r].y, w1.x, a0[r]); a1[r] = fmaf(xv[r].y, w1.y, a1[r]);
      a0[r] = fmaf(xv[r].z, w2.x, a0[r]); a1[r] = fmaf(xv[r].z, w2.y, a1[r]);
      a0[r] = fmaf(xv[r].w, w3.x, a0[r]); a1[r] = fmaf(xv[r].w, w3.y, a1[r]);
    }
  }

#pragma unroll
  for (int r = 0; r < 8; r++) {
    int row = rowBase + r;
    if (row < N) {
      float s = scale ? scale[row] : 1.f;
      *(float2*)&Y[(size_t)row * 128 + c0] = make_float2(a0[r] * s, a1[r] * s);
    }
  }
}

// ---- Aggregate + fused BN stats ----
// One row per HALF-WAVE (32 lanes x float4 = 512B/row). Edge loop unrolled
// x4 -> 4 outstanding dwordx4 gathers per lane; grid 2048 blocks for full
// wave occupancy (R3: latency-bound at 1024 blocks / no unroll).
__global__ __launch_bounds__(256) void k_agg(const float* __restrict__ HWs,
                                             const int* __restrict__ rowptr,
                                             const int* __restrict__ colx,
                                             const float* __restrict__ dinv,
                                             const float* __restrict__ bias,
                                             float* __restrict__ Y, int N,
                                             float* __restrict__ stat) {
  int lane = threadIdx.x & 63;
  int wv = threadIdx.x >> 6;
  int half = lane >> 5;
  int l32 = lane & 31;
  int c0 = 4 * l32;
  int wid = blockIdx.x * 4 + wv;
  int nw = gridDim.x * 4;
  float4 bb = *(const float4*)&bias[c0];

  float4 sa = make_float4(0.f, 0.f, 0.f, 0.f);
  float4 qa = make_float4(0.f, 0.f, 0.f, 0.f);

  for (int base = 2 * wid; base < N; base += 2 * nw) {
    int i = base + half;
    if (i < N) {
      int beg = rowptr[i];
      int end = rowptr[i + 1];
      float4 s = make_float4(0.f, 0.f, 0.f, 0.f);
      int e = beg;
#pragma unroll 1
      for (; e + 4 <= end; e += 4) {
        int i0 = colx[e + 0];
        int i1 = colx[e + 1];
        int i2 = colx[e + 2];
        int i3 = colx[e + 3];
        float4 v0 = *(const float4*)&HWs[(size_t)i0 * 128 + c0];
        float4 v1 = *(const float4*)&HWs[(size_t)i1 * 128 + c0];
        float4 v2 = *(const float4*)&HWs[(size_t)i2 * 128 + c0];
        float4 v3 = *(const float4*)&HWs[(size_t)i3 * 128 + c0];
        s.x += (v0.x + v1.x) + (v2.x + v3.x);
        s.y += (v0.y + v1.y) + (v2.y + v3.y);
        s.z += (v0.z + v1.z) + (v2.z + v3.z);
        s.w += (v0.w + v1.w) + (v2.w + v3.w);
      }
#pragma unroll 1
      for (; e < end; e++) {
        int sr = colx[e];
        float4 v = *(const float4*)&HWs[(size_t)sr * 128 + c0];
        s.x += v.x; s.y += v.y; s.z += v.z; s.w += v.w;
      }
      float di = dinv[i];
      float4 o;
      o.x = fmaf(s.x, di, bb.x);
      o.y = fmaf(s.y, di, bb.y);
      o.z = fmaf(s.z, di, bb.z);
      o.w = fmaf(s.w, di, bb.w);
      *(float4*)&Y[(size_t)i * 128 + c0] = o;
      sa.x += o.x; sa.y += o.y; sa.z += o.z; sa.w += o.w;
      qa.x += o.x * o.x; qa.y += o.y * o.y; qa.z += o.z * o.z; qa.w += o.w * o.w;
    }
  }

  __shared__ float red[8][256];   // [wave*2+half][ch: 0..127 sum, 128..255 sumsq]
  int slot = wv * 2 + half;
  *(float4*)&red[slot][c0] = sa;
  *(float4*)&red[slot][128 + c0] = qa;
  __syncthreads();
  int t = threadIdx.x;
  float v = 0.f;
#pragma unroll
  for (int s8 = 0; s8 < 8; s8++) v += red[s8][t];
  atomicAdd(&stat[t], v);
}

__global__ __launch_bounds__(128) void k_bnfinal(const float* __restrict__ stat,
                                                 const float* __restrict__ gamma,
                                                 const float* __restrict__ beta,
                                                 float invN,
                                                 float* __restrict__ scsh) {
  int c = threadIdx.x;
  float mu = stat[c] * invN;
  float var = stat[128 + c] * invN - mu * mu;
  float sc = rsqrtf(var + 1e-5f) * gamma[c];
  scsh[c] = sc;
  scsh[128 + c] = beta[c] - mu * sc;
}

// ---- Pool (fused BN+ReLU of last layer) ----
__global__ __launch_bounds__(128) void k_gstart(const int* __restrict__ batch, int N,
                                                int* __restrict__ gstart) {
  int g = threadIdx.x;
  if (g <= 64) {
    int lo = 0, hi = N;
    while (lo < hi) {
      int mid = (lo + hi) >> 1;
      if (batch[mid] < g) lo = mid + 1;
      else hi = mid;
    }
    gstart[g] = lo;   // lower_bound; gstart[64] == N
  }
}

__global__ __launch_bounds__(128) void k_pool(const float* __restrict__ H,
                                              const float* __restrict__ scsh,
                                              const int* __restrict__ gstart,
                                              float* __restrict__ pooled) {
  int g = blockIdx.x >> 3;
  int part = blockIdx.x & 7;
  int c = threadIdx.x;
  float sc = scsh[c], sh = scsh[128 + c];
  int beg = gstart[g], end = gstart[g + 1];
  int len = end - beg;
  int pbeg = beg + (len * part) / 8;
  int pend = beg + (len * (part + 1)) / 8;
  float s = 0.f;
  for (int r = pbeg; r < pend; r++) {
    float v = H[(size_t)r * 128 + c];
    s += fmaxf(fmaf(v, sc, sh), 0.f);
  }
  atomicAdd(&pooled[g * 128 + c], s);
}

// ---- Head MLP ----
__global__ __launch_bounds__(256) void k_mlp(const float* __restrict__ pooled,
                                             const int* __restrict__ gstart,
                                             const float* __restrict__ W1,
                                             const float* __restrict__ b1,
                                             const float* __restrict__ W2,
                                             const float* __restrict__ b2,
                                             float* __restrict__ out) {
  __shared__ float P[64 * 128];
  __shared__ float Z[64 * 64];
  for (int i = threadIdx.x; i < 64 * 128; i += 256) {
    int g = i >> 7;
    int cnt = gstart[g + 1] - gstart[g];
    P[i] = pooled[i] / (float)(cnt > 1 ? cnt : 1);
  }
  __syncthreads();
  for (int i = threadIdx.x; i < 64 * 64; i += 256) {
    int g = i >> 6, m = i & 63;
    float acc = b1[m];
    for (int k = 0; k < 128; k++) acc += P[(g << 7) + k] * W1[k * 64 + m];
    Z[i] = fmaxf(acc, 0.f);
  }
  __syncthreads();
  if (threadIdx.x < 64) {
    int g = threadIdx.x;
    float acc = b2[0];
    for (int m = 0; m < 64; m++) acc += Z[(g << 6) + m] * W2[m];
    out[g] = 1.f / (1.f + expf(-acc));
  }
}

// ---------------------------------------------------------------------------

extern "C" void kernel_launch(void* const* d_in, const int* in_sizes, int n_in,
                              void* d_out, int out_size, void* d_ws, size_t ws_size,
                              hipStream_t stream) {
  const float* x      = (const float*)d_in[0];
  const int*   ei     = (const int*)d_in[1];
  const int*   batch  = (const int*)d_in[2];
  const float* W_enc  = (const float*)d_in[3];
  const float* b_enc  = (const float*)d_in[4];
  const float* Wc     = (const float*)d_in[5];
  const float* bc     = (const float*)d_in[6];
  const float* gamma  = (const float*)d_in[7];
  const float* beta   = (const float*)d_in[8];
  const float* W1     = (const float*)d_in[9];
  const float* b1     = (const float*)d_in[10];
  const float* W2     = (const float*)d_in[11];
  const float* b2     = (const float*)d_in[12];
  float* out = (float*)d_out;

  const int N = in_sizes[2];         // 50000
  const int E = in_sizes[1] / 2;     // 500000
  const int NL = in_sizes[6] / 128;  // 2 layers

  size_t off = 0;
  auto alloc = [&](size_t bytes) {
    void* p = (char*)d_ws + off;
    off += (bytes + 255) & ~(size_t)255;
    return p;
  };
  float* bufA   = (float*)alloc((size_t)N * 128 * 4);
  float* bufB   = (float*)alloc((size_t)N * 128 * 4);
  int*   deg    = (int*)alloc((size_t)N * 4);
  float* dinv   = (float*)alloc((size_t)N * 4);
  int*   rowptr = (int*)alloc((size_t)(N + 1) * 4);
  int*   cursor = (int*)alloc((size_t)N * 4);
  int*   colx   = (int*)alloc((size_t)(E + N) * 4);
  int*   blksum = (int*)alloc(1024 * 4);
  float* bnstat = (float*)alloc(512 * 4);   // 2 layers x (sum[128], sumsq[128])
  float* scsh   = (float*)alloc(512 * 4);   // 2 layers x (scale[128], shift[128])
  float* pooled = (float*)alloc(64 * 128 * 4);
  int*   gstart = (int*)alloc(65 * 4);
  float* Mfold  = (float*)alloc(64 * 128 * 4);
  float* bfold  = (float*)alloc(128 * 4);

  int nbN = (N + 255) / 256;

  k_init<<<nbN, 256, 0, stream>>>(deg, pooled, bnstat, N);
  k_deg<<<(E + 255) / 256, 256, 0, stream>>>(ei, E, deg);
  k_scan_a<<<nbN, 256, 0, stream>>>(deg, N, rowptr, blksum);
  k_scan_b<<<1, 256, 0, stream>>>(blksum, nbN);
  k_scan_c<<<(N + 1 + 255) / 256, 256, 0, stream>>>(deg, N, E + N, blksum,
                                                    rowptr, cursor, dinv);
  k_fill<<<(E + N + 255) / 256, 256, 0, stream>>>(ei, E, N, cursor, colx);
  k_fold<<<65, 128, 0, stream>>>(W_enc, b_enc, Wc, Mfold, bfold);

  int gemmGrid = (N + 31) / 32;

  // layer 0 (encoder folded in): hw = (x @ M + bfold) * dinv[row]
  k_gemm<64><<<gemmGrid, 256, 0, stream>>>(x, Mfold, bfold, dinv, nullptr,
                                           bufB, N);
  k_agg<<<2048, 256, 0, stream>>>(bufB, rowptr, colx, dinv, bc, bufA, N, bnstat);
  k_bnfinal<<<1, 128, 0, stream>>>(bnstat, gamma, beta, 1.f / (float)N, scsh);

  for (int l = 1; l < NL; l++) {
    k_gemm<128><<<gemmGrid, 256, 0, stream>>>(
        bufA, Wc + (size_t)l * 128 * 128, nullptr, dinv,
        scsh + (l - 1) * 256, bufB, N);
    k_agg<<<2048, 256, 0, stream>>>(bufB, rowptr, colx, dinv, bc + l * 128,
                                    bufA, N, bnstat + l * 256);
    k_bnfinal<<<1, 128, 0, stream>>>(bnstat + l * 256, gamma + l * 128,
                                     beta + l * 128, 1.f / (float)N,
                                     scsh + l * 256);
  }

  k_gstart<<<1, 128, 0, stream>>>(batch, N, gstart);
  k_pool<<<64 * 8, 128, 0, stream>>>(bufA, scsh + (NL - 1) * 256, gstart, pooled);
  k_mlp<<<1, 256, 0, stream>>>(pooled, gstart, W1, b1, W2, b2, out);
}

// Round 6
// 384.167 us; speedup vs baseline: 1.1717x; 1.1717x over previous
//
#include <hip/hip_runtime.h>
#include <hip/hip_bf16.h>
#include <hip/hip_fp16.h>
#include <math.h>

// ---------------------------------------------------------------------------
// GCN forward on MI355X (fp32 compute; fp16 gather tables; no fp32 MFMA).
// KEY RESTRUCTURE (R5): aggregation is linear -> aggregate FIRST, GEMM after:
//   out_d = dinv_d*(sum_s dinv_s * in_s) @ W + [w_d * bfold (layer0)] + bc
// so the random gather reads the (smaller, fp16) INPUT table, not X@W.
// Evidence: R3 (occ 32%) and R5 (occ 62%) gave identical k_agg time at
// 1.8 TB/s past-L2 traffic -> bandwidth/footprint bound, not latency.
// Lessons:
//   R2: full K-unroll spills -> #pragma unroll 1 in GEMM k-loop.
//   R5: gather is past-L2-BW bound -> shrink table (fp16, 64ch for l0).
// ---------------------------------------------------------------------------

__device__ inline unsigned pack2(float a, float b) {
  union { __half2 h; unsigned u; } p;
  p.h = __floats2half2_rn(a, b);
  return p.u;
}
__device__ inline float2 unpack2(unsigned u) {
  union { unsigned u; __half2 h; } p;
  p.u = u;
  return __half22float2(p.h);
}

__global__ __launch_bounds__(256) void k_init(int* __restrict__ deg,
                                              float* __restrict__ pooled,
                                              float* __restrict__ bnstat,
                                              int N) {
  int i = blockIdx.x * 256 + threadIdx.x;
  if (i < N) deg[i] = 1;           // self-loop
  if (i < 64 * 128) pooled[i] = 0.f;
  if (i < 512) bnstat[i] = 0.f;    // sum/sumsq for both layers
}

__global__ __launch_bounds__(256) void k_deg(const int* __restrict__ ei, int E,
                                             int* __restrict__ deg) {
  int i = blockIdx.x * 256 + threadIdx.x;
  if (i < E) atomicAdd(&deg[ei[E + i]], 1);   // dst row
}

// ---- 3-kernel exclusive scan over deg[N] -> rowptr ----
__global__ __launch_bounds__(256) void k_scan_a(const int* __restrict__ deg, int N,
                                                int* __restrict__ rowptr,
                                                int* __restrict__ blksum) {
  __shared__ int s[256];
  int t = threadIdx.x;
  int i = blockIdx.x * 256 + t;
  int v = (i < N) ? deg[i] : 0;
  s[t] = v;
  __syncthreads();
  for (int off = 1; off < 256; off <<= 1) {
    int x = (t >= off) ? s[t - off] : 0;
    __syncthreads();
    s[t] += x;
    __syncthreads();
  }
  if (i < N) rowptr[i] = s[t] - v;            // exclusive (partial)
  if (t == 255) blksum[blockIdx.x] = s[255];
}

__global__ __launch_bounds__(256) void k_scan_b(int* __restrict__ blksum, int nb) {
  __shared__ int s[256];
  int t = threadIdx.x;
  int v = (t < nb) ? blksum[t] : 0;
  s[t] = v;
  __syncthreads();
  for (int off = 1; off < 256; off <<= 1) {
    int x = (t >= off) ? s[t - off] : 0;
    __syncthreads();
    s[t] += x;
    __syncthreads();
  }
  if (t < nb) blksum[t] = s[t] - v;           // exclusive
}

__global__ __launch_bounds__(256) void k_scan_c(const int* __restrict__ deg, int N,
                                                int total,
                                                const int* __restrict__ blksum,
                                                int* __restrict__ rowptr,
                                                int* __restrict__ cursor,
                                                float* __restrict__ dinv) {
  int i = blockIdx.x * 256 + threadIdx.x;
  if (i < N) {
    int rp = rowptr[i] + blksum[blockIdx.x];
    rowptr[i] = rp;
    cursor[i] = rp;
    dinv[i] = rsqrtf((float)deg[i]);
  } else if (i == N) {
    rowptr[N] = total;
  }
}

__global__ __launch_bounds__(256) void k_fill(const int* __restrict__ ei, int E, int N,
                                              int* __restrict__ cursor,
                                              int* __restrict__ colx) {
  int i = blockIdx.x * 256 + threadIdx.x;
  if (i < E) {
    int s = ei[i];
    int d = ei[E + i];
    int pos = atomicAdd(&cursor[d], 1);
    colx[pos] = s;
  } else if (i < E + N) {
    int j = i - E;
    int pos = atomicAdd(&cursor[j], 1);
    colx[pos] = j;                           // self-loop entry
  }
}

// ---- Fold encoder into layer-0 weights: M = W_enc @ Wc0, bfold = b_enc @ Wc0
__global__ __launch_bounds__(128) void k_fold(const float* __restrict__ W_enc,
                                              const float* __restrict__ b_enc,
                                              const float* __restrict__ Wc0,
                                              float* __restrict__ M,
                                              float* __restrict__ bfold) {
  int n = threadIdx.x;                 // 0..127
  int k = blockIdx.x;                  // 0..64 (64 == bias row)
  const float* arow = (k < 64) ? (W_enc + (size_t)k * 128) : b_enc;
  float acc = 0.f;
  for (int j = 0; j < 128; j++) acc = fmaf(arow[j], Wc0[(size_t)j * 128 + n], acc);
  if (k < 64) M[(size_t)k * 128 + n] = acc;
  else bfold[n] = acc;
}

// ---- prep0: xs[row][64] fp16 = x[row] * dinv[row] ----
__global__ __launch_bounds__(256) void k_prep0(const float* __restrict__ x,
                                               const float* __restrict__ dinv,
                                               unsigned* __restrict__ xs2, // uint2 view below
                                               int total /* N*16 */) {
  int i = blockIdx.x * 256 + threadIdx.x;
  if (i < total) {
    int row = i >> 4;
    float4 v = ((const float4*)x)[i];
    float d = dinv[row];
    uint2 o;
    o.x = pack2(v.x * d, v.y * d);
    o.y = pack2(v.z * d, v.w * d);
    ((uint2*)xs2)[i] = o;
  }
}

// ---- prep1: hs[row][128] fp16 = relu(h*sc+sh) * dinv[row] ----
__global__ __launch_bounds__(256) void k_prep1(const float* __restrict__ H,
                                               const float* __restrict__ scsh,
                                               const float* __restrict__ dinv,
                                               unsigned* __restrict__ hs2,
                                               int total /* N*32 */) {
  int i = blockIdx.x * 256 + threadIdx.x;
  if (i < total) {
    int row = i >> 5;
    int c4 = i & 31;
    float4 v = ((const float4*)H)[i];
    float4 sc = ((const float4*)scsh)[c4];
    float4 sh = ((const float4*)(scsh + 128))[c4];
    float d = dinv[row];
    float a = fmaxf(fmaf(v.x, sc.x, sh.x), 0.f) * d;
    float b = fmaxf(fmaf(v.y, sc.y, sh.y), 0.f) * d;
    float c = fmaxf(fmaf(v.z, sc.z, sh.z), 0.f) * d;
    float e = fmaxf(fmaf(v.w, sc.w, sh.w), 0.f) * d;
    uint2 o;
    o.x = pack2(a, b);
    o.y = pack2(c, e);
    ((uint2*)hs2)[i] = o;
  }
}

// ---- agg0: ax[i][64] = dinv_i * sum_{s in row i} xs[s]; w[i] = dinv_i*sum dinv_s
// half-wave per row: 32 lanes x 4B (half2) = 64 ch.
__global__ __launch_bounds__(256) void k_agg0(const unsigned* __restrict__ xs,
                                              const int* __restrict__ rowptr,
                                              const int* __restrict__ colx,
                                              const float* __restrict__ dinv,
                                              float* __restrict__ ax,
                                              float* __restrict__ w, int N) {
  int lane = threadIdx.x & 63;
  int wv = threadIdx.x >> 6;
  int half = lane >> 5;
  int l32 = lane & 31;
  int wid = blockIdx.x * 4 + wv;
  int nw = gridDim.x * 4;

  for (int base = 2 * wid; base < N; base += 2 * nw) {
    int i = base + half;
    if (i < N) {
      int beg = rowptr[i];
      int end = rowptr[i + 1];
      float sx = 0.f, sy = 0.f, sd = 0.f;
      int e = beg;
#pragma unroll 1
      for (; e + 4 <= end; e += 4) {
        int i0 = colx[e + 0], i1 = colx[e + 1], i2 = colx[e + 2], i3 = colx[e + 3];
        unsigned v0 = xs[(size_t)i0 * 32 + l32];
        unsigned v1 = xs[(size_t)i1 * 32 + l32];
        unsigned v2 = xs[(size_t)i2 * 32 + l32];
        unsigned v3 = xs[(size_t)i3 * 32 + l32];
        float d0 = dinv[i0], d1 = dinv[i1], d2 = dinv[i2], d3 = dinv[i3];
        float2 f0 = unpack2(v0), f1 = unpack2(v1), f2 = unpack2(v2), f3 = unpack2(v3);
        sx += (f0.x + f1.x) + (f2.x + f3.x);
        sy += (f0.y + f1.y) + (f2.y + f3.y);
        sd += (d0 + d1) + (d2 + d3);
      }
#pragma unroll 1
      for (; e < end; e++) {
        int sr = colx[e];
        float2 f = unpack2(xs[(size_t)sr * 32 + l32]);
        sx += f.x;
        sy += f.y;
        sd += dinv[sr];
      }
      float di = dinv[i];
      ((float2*)ax)[(size_t)i * 32 + l32] = make_float2(sx * di, sy * di);
      if (l32 == 0) w[i] = di * sd;
    }
  }
}

// ---- agg1: a1[i][128] = dinv_i * sum_{s in row i} hs[s] ----
// half-wave per row: 32 lanes x 8B (2x half2) = 128 ch.
__global__ __launch_bounds__(256) void k_agg1(const uint2* __restrict__ hs,
                                              const int* __restrict__ rowptr,
                                              const int* __restrict__ colx,
                                              const float* __restrict__ dinv,
                                              float* __restrict__ a1, int N) {
  int lane = threadIdx.x & 63;
  int wv = threadIdx.x >> 6;
  int half = lane >> 5;
  int l32 = lane & 31;
  int wid = blockIdx.x * 4 + wv;
  int nw = gridDim.x * 4;

  for (int base = 2 * wid; base < N; base += 2 * nw) {
    int i = base + half;
    if (i < N) {
      int beg = rowptr[i];
      int end = rowptr[i + 1];
      float4 s = make_float4(0.f, 0.f, 0.f, 0.f);
      int e = beg;
#pragma unroll 1
      for (; e + 4 <= end; e += 4) {
        int i0 = colx[e + 0], i1 = colx[e + 1], i2 = colx[e + 2], i3 = colx[e + 3];
        uint2 v0 = hs[(size_t)i0 * 32 + l32];
        uint2 v1 = hs[(size_t)i1 * 32 + l32];
        uint2 v2 = hs[(size_t)i2 * 32 + l32];
        uint2 v3 = hs[(size_t)i3 * 32 + l32];
        float2 a0 = unpack2(v0.x), b0 = unpack2(v0.y);
        float2 a1f = unpack2(v1.x), b1f = unpack2(v1.y);
        float2 a2 = unpack2(v2.x), b2 = unpack2(v2.y);
        float2 a3 = unpack2(v3.x), b3 = unpack2(v3.y);
        s.x += (a0.x + a1f.x) + (a2.x + a3.x);
        s.y += (a0.y + a1f.y) + (a2.y + a3.y);
        s.z += (b0.x + b1f.x) + (b2.x + b3.x);
        s.w += (b0.y + b1f.y) + (b2.y + b3.y);
      }
#pragma unroll 1
      for (; e < end; e++) {
        int sr = colx[e];
        uint2 v = hs[(size_t)sr * 32 + l32];
        float2 a = unpack2(v.x), b = unpack2(v.y);
        s.x += a.x; s.y += a.y; s.z += b.x; s.w += b.y;
      }
      float di = dinv[i];
      ((float4*)a1)[(size_t)i * 32 + l32] =
          make_float4(s.x * di, s.y * di, s.z * di, s.w * di);
    }
  }
}

// ---- GEMM: Y[N][128] = X[N][K] @ W[K][128] + bias (+ wvec[row]*bias2) ----
// Fused per-channel BN stats (sum/sumsq of Y) -> stat[256] via LDS + atomics.
template <int K>
__global__ __launch_bounds__(256, 2) void k_gemm(const float* __restrict__ X,
                                                 const float* __restrict__ W,
                                                 const float* __restrict__ bias,
                                                 const float* __restrict__ wvec,
                                                 const float* __restrict__ bias2,
                                                 float* __restrict__ stat,
                                                 float* __restrict__ Y, int N) {
  __shared__ float Wl[K * 128];
  __shared__ float Xl[32 * K];   // reused as red[4][256] after the k-loop
  const int K4 = K / 4;

  for (int i = threadIdx.x; i < K * 32; i += 256)   // K*128/4 float4s
    ((float4*)Wl)[i] = ((const float4*)W)[i];

  int rowBlk = blockIdx.x * 32;
  for (int i = threadIdx.x; i < 32 * K4; i += 256) {
    int r = i / K4, c4 = i - r * K4;
    int row = rowBlk + r;
    if (row >= N) row = N - 1;                      // clamp (writes guarded)
    ((float4*)Xl)[i] = ((const float4*)(X + (size_t)row * K))[c4];
  }
  __syncthreads();

  int lane = threadIdx.x & 63;
  int wv = threadIdx.x >> 6;
  int c0 = 2 * lane;
  int lr0 = wv * 8;
  int rowBase = rowBlk + lr0;

  float2 bb = *(const float2*)&bias[c0];
  float2 b2 = make_float2(0.f, 0.f);
  if (bias2) b2 = *(const float2*)&bias2[c0];

  float a0[8], a1[8];
#pragma unroll
  for (int r = 0; r < 8; r++) { a0[r] = bb.x; a1[r] = bb.y; }

#pragma unroll 1
  for (int k = 0; k < K; k += 4) {
    float2 w0 = *(const float2*)&Wl[(k + 0) * 128 + c0];
    float2 w1 = *(const float2*)&Wl[(k + 1) * 128 + c0];
    float2 w2 = *(const float2*)&Wl[(k + 2) * 128 + c0];
    float2 w3 = *(const float2*)&Wl[(k + 3) * 128 + c0];
    float4 xv[8];
#pragma unroll
    for (int r = 0; r < 8; r++)
      xv[r] = *(const float4*)&Xl[(lr0 + r) * K + k];
#pragma unroll
    for (int r = 0; r < 8; r++) {
      a0[r] = fmaf(xv[r].x, w0.x, a0[r]); a1[r] = fmaf(xv[r].x, w0.y, a1[r]);
      a0[r] = fmaf(xv[r].y, w1.x, a0[r]); a1[r] = fmaf(xv[r].y, w1.y, a1[r]);
      a0[r] = fmaf(xv[r].z, w2.x, a0[r]); a1[r] = fmaf(xv[r].z, w2.y, a1[r]);
      a0[r] = fmaf(xv[r].w, w3.x, a0[r]); a1[r] = fmaf(xv[r].w, w3.y, a1[r]);
    }
  }

  float s0 = 0.f, s1 = 0.f, q0 = 0.f, q1 = 0.f;
#pragma unroll
  for (int r = 0; r < 8; r++) {
    int row = rowBase + r;
    if (row < N) {
      float o0 = a0[r], o1 = a1[r];
      if (wvec) {
        float wr = wvec[row];
        o0 = fmaf(wr, b2.x, o0);
        o1 = fmaf(wr, b2.y, o1);
      }
      *(float2*)&Y[(size_t)row * 128 + c0] = make_float2(o0, o1);
      s0 += o0; q0 += o0 * o0;
      s1 += o1; q1 += o1 * o1;
    }
  }

  // BN stats: reuse Xl as red[4][256] (all waves done reading Xl)
  __syncthreads();
  float* red = (float*)Xl;
  red[wv * 256 + c0] = s0;
  red[wv * 256 + c0 + 1] = s1;
  red[wv * 256 + 128 + c0] = q0;
  red[wv * 256 + 128 + c0 + 1] = q1;
  __syncthreads();
  int t = threadIdx.x;
  float v = red[t] + red[256 + t] + red[512 + t] + red[768 + t];
  atomicAdd(&stat[t], v);
}

__global__ __launch_bounds__(128) void k_bnfinal(const float* __restrict__ stat,
                                                 const float* __restrict__ gamma,
                                                 const float* __restrict__ beta,
                                                 float invN,
                                                 float* __restrict__ scsh) {
  int c = threadIdx.x;
  float mu = stat[c] * invN;
  float var = stat[128 + c] * invN - mu * mu;
  float sc = rsqrtf(var + 1e-5f) * gamma[c];
  scsh[c] = sc;
  scsh[128 + c] = beta[c] - mu * sc;
}

// ---- Pool (fused BN+ReLU of last layer) ----
__global__ __launch_bounds__(128) void k_gstart(const int* __restrict__ batch, int N,
                                                int* __restrict__ gstart) {
  int g = threadIdx.x;
  if (g <= 64) {
    int lo = 0, hi = N;
    while (lo < hi) {
      int mid = (lo + hi) >> 1;
      if (batch[mid] < g) lo = mid + 1;
      else hi = mid;
    }
    gstart[g] = lo;   // lower_bound; gstart[64] == N
  }
}

__global__ __launch_bounds__(128) void k_pool(const float* __restrict__ H,
                                              const float* __restrict__ scsh,
                                              const int* __restrict__ gstart,
                                              float* __restrict__ pooled) {
  int g = blockIdx.x >> 3;
  int part = blockIdx.x & 7;
  int c = threadIdx.x;
  float sc = scsh[c], sh = scsh[128 + c];
  int beg = gstart[g], end = gstart[g + 1];
  int len = end - beg;
  int pbeg = beg + (len * part) / 8;
  int pend = beg + (len * (part + 1)) / 8;
  float s = 0.f;
  for (int r = pbeg; r < pend; r++) {
    float v = H[(size_t)r * 128 + c];
    s += fmaxf(fmaf(v, sc, sh), 0.f);
  }
  atomicAdd(&pooled[g * 128 + c], s);
}

// ---- Head MLP ----
__global__ __launch_bounds__(256) void k_mlp(const float* __restrict__ pooled,
                                             const int* __restrict__ gstart,
                                             const float* __restrict__ W1,
                                             const float* __restrict__ b1,
                                             const float* __restrict__ W2,
                                             const float* __restrict__ b2,
                                             float* __restrict__ out) {
  __shared__ float P[64 * 128];
  __shared__ float Z[64 * 64];
  for (int i = threadIdx.x; i < 64 * 128; i += 256) {
    int g = i >> 7;
    int cnt = gstart[g + 1] - gstart[g];
    P[i] = pooled[i] / (float)(cnt > 1 ? cnt : 1);
  }
  __syncthreads();
  for (int i = threadIdx.x; i < 64 * 64; i += 256) {
    int g = i >> 6, m = i & 63;
    float acc = b1[m];
    for (int k = 0; k < 128; k++) acc += P[(g << 7) + k] * W1[k * 64 + m];
    Z[i] = fmaxf(acc, 0.f);
  }
  __syncthreads();
  if (threadIdx.x < 64) {
    int g = threadIdx.x;
    float acc = b2[0];
    for (int m = 0; m < 64; m++) acc += Z[(g << 6) + m] * W2[m];
    out[g] = 1.f / (1.f + expf(-acc));
  }
}

// ---------------------------------------------------------------------------

extern "C" void kernel_launch(void* const* d_in, const int* in_sizes, int n_in,
                              void* d_out, int out_size, void* d_ws, size_t ws_size,
                              hipStream_t stream) {
  const float* x      = (const float*)d_in[0];
  const int*   ei     = (const int*)d_in[1];
  const int*   batch  = (const int*)d_in[2];
  const float* W_enc  = (const float*)d_in[3];
  const float* b_enc  = (const float*)d_in[4];
  const float* Wc     = (const float*)d_in[5];
  const float* bc     = (const float*)d_in[6];
  const float* gamma  = (const float*)d_in[7];
  const float* beta   = (const float*)d_in[8];
  const float* W1     = (const float*)d_in[9];
  const float* b1     = (const float*)d_in[10];
  const float* W2     = (const float*)d_in[11];
  const float* b2     = (const float*)d_in[12];
  float* out = (float*)d_out;

  const int N = in_sizes[2];         // 50000
  const int E = in_sizes[1] / 2;     // 500000
  const int NL = in_sizes[6] / 128;  // 2 layers

  size_t off = 0;
  auto alloc = [&](size_t bytes) {
    void* p = (char*)d_ws + off;
    off += (bytes + 255) & ~(size_t)255;
    return p;
  };
  float* bufA   = (float*)alloc((size_t)N * 128 * 4);  // h1 / h2
  float* bufB   = (float*)alloc((size_t)N * 128 * 4);  // ax (N*64) / a1 (N*128)
  int*   deg    = (int*)alloc((size_t)N * 4);
  float* dinv   = (float*)alloc((size_t)N * 4);
  int*   rowptr = (int*)alloc((size_t)(N + 1) * 4);
  int*   cursor = (int*)alloc((size_t)N * 4);
  int*   colx   = (int*)alloc((size_t)(E + N) * 4);
  int*   blksum = (int*)alloc(1024 * 4);
  float* bnstat = (float*)alloc(512 * 4);   // 2 layers x (sum[128], sumsq[128])
  float* scsh   = (float*)alloc(512 * 4);   // 2 layers x (scale[128], shift[128])
  float* pooled = (float*)alloc(64 * 128 * 4);
  int*   gstart = (int*)alloc(65 * 4);
  float* Mfold  = (float*)alloc(64 * 128 * 4);
  float* bfold  = (float*)alloc(128 * 4);
  unsigned* xs  = (unsigned*)alloc((size_t)N * 64 * 2);   // fp16 x*dinv
  unsigned* hs  = (unsigned*)alloc((size_t)N * 128 * 2);  // fp16 f(h)*dinv
  float* wv     = (float*)alloc((size_t)N * 4);           // w_i for layer0 bias

  int nbN = (N + 255) / 256;

  k_init<<<nbN, 256, 0, stream>>>(deg, pooled, bnstat, N);
  k_deg<<<(E + 255) / 256, 256, 0, stream>>>(ei, E, deg);
  k_scan_a<<<nbN, 256, 0, stream>>>(deg, N, rowptr, blksum);
  k_scan_b<<<1, 256, 0, stream>>>(blksum, nbN);
  k_scan_c<<<(N + 1 + 255) / 256, 256, 0, stream>>>(deg, N, E + N, blksum,
                                                    rowptr, cursor, dinv);
  k_fill<<<(E + N + 255) / 256, 256, 0, stream>>>(ei, E, N, cursor, colx);
  k_fold<<<65, 128, 0, stream>>>(W_enc, b_enc, Wc, Mfold, bfold);

  int gemmGrid = (N + 31) / 32;

  // ---- layer 0: agg(x) -> GEMM with folded encoder ----
  k_prep0<<<(N * 16 + 255) / 256, 256, 0, stream>>>(x, dinv, xs, N * 16);
  k_agg0<<<2048, 256, 0, stream>>>(xs, rowptr, colx, dinv, bufB, wv, N);
  k_gemm<64><<<gemmGrid, 256, 0, stream>>>(bufB, Mfold, bc, wv, bfold,
                                           bnstat, bufA, N);
  k_bnfinal<<<1, 128, 0, stream>>>(bnstat, gamma, beta, 1.f / (float)N, scsh);

  // ---- layers 1..NL-1: prep(f) -> agg -> GEMM ----
  for (int l = 1; l < NL; l++) {
    k_prep1<<<(N * 32 + 255) / 256, 256, 0, stream>>>(
        bufA, scsh + (l - 1) * 256, dinv, hs, N * 32);
    k_agg1<<<2048, 256, 0, stream>>>((const uint2*)hs, rowptr, colx, dinv,
                                     bufB, N);
    k_gemm<128><<<gemmGrid, 256, 0, stream>>>(
        bufB, Wc + (size_t)l * 128 * 128, bc + l * 128, nullptr, nullptr,
        bnstat + l * 256, bufA, N);
    k_bnfinal<<<1, 128, 0, stream>>>(bnstat + l * 256, gamma + l * 128,
                                     beta + l * 128, 1.f / (float)N,
                                     scsh + l * 256);
  }

  k_gstart<<<1, 128, 0, stream>>>(batch, N, gstart);
  k_pool<<<64 * 8, 128, 0, stream>>>(bufA, scsh + (NL - 1) * 256, gstart, pooled);
  k_mlp<<<1, 256, 0, stream>>>(pooled, gstart, W1, b1, W2, b2, out);
}

// Round 7
// 367.434 us; speedup vs baseline: 1.2250x; 1.0455x over previous
//
#include <hip/hip_runtime.h>
#include <hip/hip_bf16.h>
#include <hip/hip_fp16.h>
#include <math.h>

// ---------------------------------------------------------------------------
// GCN forward on MI355X. fp16 gather tables + fp16 MFMA GEMMs (fp32 accum).
// Structure (R5): aggregate FIRST (linear), GEMM after:
//   l0: ax = dinv_d*sum(dinv_s*x_s) ; h1 = ax@M + w_d*bfold + bc0   [MFMA K=64]
//   l1: a1 = dinv_d*sum(dinv_s*BNReLU(h1)_s); h2 = a1@Wc1 + bc1     [MFMA K=128]
//   pool(BN+ReLU fused) -> MLP -> sigmoid
// Lessons:
//   R2: full fp32-K unroll spills -> (fp32 GEMM removed entirely this round)
//   R5: gather is past-L2-BW bound -> fp16 tables, aggregate-first.
//   R6: fp32 VALU GEMM stuck at 69us (VALUBusy 26%, occ 16%, 80KB LDS);
//       matrix pipe idle -> v_mfma_f32_16x16x32_f16, W transposed fp16,
//       LDS rows padded +8 fp16 (16B-aligned, <=2 lanes/bank).
// ---------------------------------------------------------------------------

typedef _Float16 f16x8 __attribute__((ext_vector_type(8)));
typedef float f32x4 __attribute__((ext_vector_type(4)));

__device__ inline unsigned pack2(float a, float b) {
  union { __half2 h; unsigned u; } p;
  p.h = __floats2half2_rn(a, b);
  return p.u;
}
__device__ inline float2 unpack2(unsigned u) {
  union { unsigned u; __half2 h; } p;
  p.u = u;
  return __half22float2(p.h);
}

__global__ __launch_bounds__(256) void k_init(int* __restrict__ deg,
                                              float* __restrict__ pooled,
                                              float* __restrict__ bnstat,
                                              int N) {
  int i = blockIdx.x * 256 + threadIdx.x;
  if (i < N) deg[i] = 1;           // self-loop
  if (i < 64 * 128) pooled[i] = 0.f;
  if (i < 512) bnstat[i] = 0.f;    // sum/sumsq for both layers
}

__global__ __launch_bounds__(256) void k_deg(const int* __restrict__ ei, int E,
                                             int* __restrict__ deg) {
  int i = blockIdx.x * 256 + threadIdx.x;
  if (i < E) atomicAdd(&deg[ei[E + i]], 1);   // dst row
}

// ---- 3-kernel exclusive scan over deg[N] -> rowptr ----
__global__ __launch_bounds__(256) void k_scan_a(const int* __restrict__ deg, int N,
                                                int* __restrict__ rowptr,
                                                int* __restrict__ blksum) {
  __shared__ int s[256];
  int t = threadIdx.x;
  int i = blockIdx.x * 256 + t;
  int v = (i < N) ? deg[i] : 0;
  s[t] = v;
  __syncthreads();
  for (int off = 1; off < 256; off <<= 1) {
    int x = (t >= off) ? s[t - off] : 0;
    __syncthreads();
    s[t] += x;
    __syncthreads();
  }
  if (i < N) rowptr[i] = s[t] - v;            // exclusive (partial)
  if (t == 255) blksum[blockIdx.x] = s[255];
}

__global__ __launch_bounds__(256) void k_scan_b(int* __restrict__ blksum, int nb) {
  __shared__ int s[256];
  int t = threadIdx.x;
  int v = (t < nb) ? blksum[t] : 0;
  s[t] = v;
  __syncthreads();
  for (int off = 1; off < 256; off <<= 1) {
    int x = (t >= off) ? s[t - off] : 0;
    __syncthreads();
    s[t] += x;
    __syncthreads();
  }
  if (t < nb) blksum[t] = s[t] - v;           // exclusive
}

__global__ __launch_bounds__(256) void k_scan_c(const int* __restrict__ deg, int N,
                                                int total,
                                                const int* __restrict__ blksum,
                                                int* __restrict__ rowptr,
                                                int* __restrict__ cursor,
                                                float* __restrict__ dinv) {
  int i = blockIdx.x * 256 + threadIdx.x;
  if (i < N) {
    int rp = rowptr[i] + blksum[blockIdx.x];
    rowptr[i] = rp;
    cursor[i] = rp;
    dinv[i] = rsqrtf((float)deg[i]);
  } else if (i == N) {
    rowptr[N] = total;
  }
}

__global__ __launch_bounds__(256) void k_fill(const int* __restrict__ ei, int E, int N,
                                              int* __restrict__ cursor,
                                              int* __restrict__ colx) {
  int i = blockIdx.x * 256 + threadIdx.x;
  if (i < E) {
    int s = ei[i];
    int d = ei[E + i];
    int pos = atomicAdd(&cursor[d], 1);
    colx[pos] = s;
  } else if (i < E + N) {
    int j = i - E;
    int pos = atomicAdd(&cursor[j], 1);
    colx[pos] = j;                           // self-loop entry
  }
}

// ---- Fold encoder: MT[n][k] = fp16((W_enc @ Wc0)[k][n]); bfold = b_enc @ Wc0
__global__ __launch_bounds__(128) void k_fold(const float* __restrict__ W_enc,
                                              const float* __restrict__ b_enc,
                                              const float* __restrict__ Wc0,
                                              unsigned short* __restrict__ MT,
                                              float* __restrict__ bfold) {
  int n = threadIdx.x;                 // 0..127
  int k = blockIdx.x;                  // 0..64 (64 == bias row)
  const float* arow = (k < 64) ? (W_enc + (size_t)k * 128) : b_enc;
  float acc = 0.f;
  for (int j = 0; j < 128; j++) acc = fmaf(arow[j], Wc0[(size_t)j * 128 + n], acc);
  if (k < 64) ((__half*)MT)[(size_t)n * 64 + k] = __float2half(acc);
  else bfold[n] = acc;
}

// ---- transpose+cast a 128x128 fp32 W into fp16 WT[n][k] ----
__global__ __launch_bounds__(256) void k_wprep(const float* __restrict__ Wsrc,
                                               unsigned short* __restrict__ WT) {
  int i = blockIdx.x * 256 + threadIdx.x;   // 16384
  int n = i & 127, k = i >> 7;              // coalesced read
  ((__half*)WT)[(size_t)n * 128 + k] = __float2half(Wsrc[i]);
}

// ---- prep0: xs[row][64] fp16 = x[row] * dinv[row] ----
__global__ __launch_bounds__(256) void k_prep0(const float* __restrict__ x,
                                               const float* __restrict__ dinv,
                                               unsigned* __restrict__ xs2,
                                               int total /* N*16 */) {
  int i = blockIdx.x * 256 + threadIdx.x;
  if (i < total) {
    int row = i >> 4;
    float4 v = ((const float4*)x)[i];
    float d = dinv[row];
    uint2 o;
    o.x = pack2(v.x * d, v.y * d);
    o.y = pack2(v.z * d, v.w * d);
    ((uint2*)xs2)[i] = o;
  }
}

// ---- prep1: hs[row][128] fp16 = relu(h*sc+sh) * dinv[row] ----
__global__ __launch_bounds__(256) void k_prep1(const float* __restrict__ H,
                                               const float* __restrict__ scsh,
                                               const float* __restrict__ dinv,
                                               unsigned* __restrict__ hs2,
                                               int total /* N*32 */) {
  int i = blockIdx.x * 256 + threadIdx.x;
  if (i < total) {
    int row = i >> 5;
    int c4 = i & 31;
    float4 v = ((const float4*)H)[i];
    float4 sc = ((const float4*)scsh)[c4];
    float4 sh = ((const float4*)(scsh + 128))[c4];
    float d = dinv[row];
    float a = fmaxf(fmaf(v.x, sc.x, sh.x), 0.f) * d;
    float b = fmaxf(fmaf(v.y, sc.y, sh.y), 0.f) * d;
    float c = fmaxf(fmaf(v.z, sc.z, sh.z), 0.f) * d;
    float e = fmaxf(fmaf(v.w, sc.w, sh.w), 0.f) * d;
    uint2 o;
    o.x = pack2(a, b);
    o.y = pack2(c, e);
    ((uint2*)hs2)[i] = o;
  }
}

// ---- agg0: axh[i][64] fp16 = dinv_i * sum xs[s]; w[i] = dinv_i * sum dinv_s
__global__ __launch_bounds__(256) void k_agg0(const unsigned* __restrict__ xs,
                                              const int* __restrict__ rowptr,
                                              const int* __restrict__ colx,
                                              const float* __restrict__ dinv,
                                              unsigned* __restrict__ axh,
                                              float* __restrict__ w, int N) {
  int lane = threadIdx.x & 63;
  int wv = threadIdx.x >> 6;
  int half = lane >> 5;
  int l32 = lane & 31;
  int wid = blockIdx.x * 4 + wv;
  int nw = gridDim.x * 4;

  for (int base = 2 * wid; base < N; base += 2 * nw) {
    int i = base + half;
    if (i < N) {
      int beg = rowptr[i];
      int end = rowptr[i + 1];
      float sx = 0.f, sy = 0.f, sd = 0.f;
      int e = beg;
#pragma unroll 1
      for (; e + 4 <= end; e += 4) {
        int i0 = colx[e + 0], i1 = colx[e + 1], i2 = colx[e + 2], i3 = colx[e + 3];
        unsigned v0 = xs[(size_t)i0 * 32 + l32];
        unsigned v1 = xs[(size_t)i1 * 32 + l32];
        unsigned v2 = xs[(size_t)i2 * 32 + l32];
        unsigned v3 = xs[(size_t)i3 * 32 + l32];
        float d0 = dinv[i0], d1 = dinv[i1], d2 = dinv[i2], d3 = dinv[i3];
        float2 f0 = unpack2(v0), f1 = unpack2(v1), f2 = unpack2(v2), f3 = unpack2(v3);
        sx += (f0.x + f1.x) + (f2.x + f3.x);
        sy += (f0.y + f1.y) + (f2.y + f3.y);
        sd += (d0 + d1) + (d2 + d3);
      }
#pragma unroll 1
      for (; e < end; e++) {
        int sr = colx[e];
        float2 f = unpack2(xs[(size_t)sr * 32 + l32]);
        sx += f.x;
        sy += f.y;
        sd += dinv[sr];
      }
      float di = dinv[i];
      axh[(size_t)i * 32 + l32] = pack2(sx * di, sy * di);
      if (l32 == 0) w[i] = di * sd;
    }
  }
}

// ---- agg1: a1h[i][128] fp16 = dinv_i * sum hs[s] ----
__global__ __launch_bounds__(256) void k_agg1(const uint2* __restrict__ hs,
                                              const int* __restrict__ rowptr,
                                              const int* __restrict__ colx,
                                              const float* __restrict__ dinv,
                                              uint2* __restrict__ a1h, int N) {
  int lane = threadIdx.x & 63;
  int wv = threadIdx.x >> 6;
  int half = lane >> 5;
  int l32 = lane & 31;
  int wid = blockIdx.x * 4 + wv;
  int nw = gridDim.x * 4;

  for (int base = 2 * wid; base < N; base += 2 * nw) {
    int i = base + half;
    if (i < N) {
      int beg = rowptr[i];
      int end = rowptr[i + 1];
      float4 s = make_float4(0.f, 0.f, 0.f, 0.f);
      int e = beg;
#pragma unroll 1
      for (; e + 4 <= end; e += 4) {
        int i0 = colx[e + 0], i1 = colx[e + 1], i2 = colx[e + 2], i3 = colx[e + 3];
        uint2 v0 = hs[(size_t)i0 * 32 + l32];
        uint2 v1 = hs[(size_t)i1 * 32 + l32];
        uint2 v2 = hs[(size_t)i2 * 32 + l32];
        uint2 v3 = hs[(size_t)i3 * 32 + l32];
        float2 a0 = unpack2(v0.x), b0 = unpack2(v0.y);
        float2 a1f = unpack2(v1.x), b1f = unpack2(v1.y);
        float2 a2 = unpack2(v2.x), b2 = unpack2(v2.y);
        float2 a3 = unpack2(v3.x), b3 = unpack2(v3.y);
        s.x += (a0.x + a1f.x) + (a2.x + a3.x);
        s.y += (a0.y + a1f.y) + (a2.y + a3.y);
        s.z += (b0.x + b1f.x) + (b2.x + b3.x);
        s.w += (b0.y + b1f.y) + (b2.y + b3.y);
      }
#pragma unroll 1
      for (; e < end; e++) {
        int sr = colx[e];
        uint2 v = hs[(size_t)sr * 32 + l32];
        float2 a = unpack2(v.x), b = unpack2(v.y);
        s.x += a.x; s.y += a.y; s.z += b.x; s.w += b.y;
      }
      float di = dinv[i];
      a1h[(size_t)i * 32 + l32] =
          make_uint2(pack2(s.x * di, s.y * di), pack2(s.z * di, s.w * di));
    }
  }
}

// ---- MFMA GEMM: Y[N][128] = Xh[N][K](fp16) @ W(fp16,WT[n][k]) + bias
//                 (+ wvec[row]*bias2[col]) ; fused BN stats -> stat[256].
// Block: 256 thr / 4 waves; 32 rows. Wave (wr,wc): rows wr*16+.., cols wc*64+..
// A-frag: lane&15 = row, (lane>>4)*8+i = k (contig 8 fp16 -> b128).
// B-frag: lane&15 = col (from WT row), same k pattern.
// C (m89-verified): row=(lane>>4)*4+reg, col=lane&15.
// LDS rows padded +8 fp16: 16B-aligned, banks spread (<=2 lanes/bank).
template <int K>
__global__ __launch_bounds__(256) void k_gemm_f16(
    const unsigned short* __restrict__ Xh,   // N x K fp16
    const unsigned short* __restrict__ WT,   // 128 x K fp16 (n-major)
    const float* __restrict__ bias,          // [128]
    const float* __restrict__ wvec,          // [N] or null (layer0)
    const float* __restrict__ bias2,         // [128] or null (layer0)
    float* __restrict__ stat,                // [256] sum/sumsq
    float* __restrict__ Y, int N) {
  constexpr int KP = K + 8;
  constexpr int K8 = K / 8;
  __shared__ unsigned short Xl[32 * KP];
  __shared__ unsigned short Wl[128 * KP];
  __shared__ float red[2][2][128];

  int rowBlk = blockIdx.x * 32;
  for (int i = threadIdx.x; i < 32 * K8; i += 256) {
    int r = i / K8, c = i - r * K8;
    int row = rowBlk + r;
    if (row >= N) row = N - 1;               // clamp (stores guarded)
    uint4 v = ((const uint4*)(Xh + (size_t)row * K))[c];
    *(uint4*)&Xl[r * KP + c * 8] = v;
  }
  for (int i = threadIdx.x; i < 128 * K8; i += 256) {
    int r = i / K8, c = i - r * K8;
    uint4 v = ((const uint4*)(WT + (size_t)r * K))[c];
    *(uint4*)&Wl[r * KP + c * 8] = v;
  }
  __syncthreads();

  int lane = threadIdx.x & 63;
  int wv = threadIdx.x >> 6;
  int wr = wv & 1;           // row half
  int wc = wv >> 1;          // col half
  int l15 = lane & 15;
  int kg = lane >> 4;        // k-group 0..3

  f32x4 acc[4];
#pragma unroll
  for (int t = 0; t < 4; t++) acc[t] = {0.f, 0.f, 0.f, 0.f};

  const unsigned short* xa = &Xl[(wr * 16 + l15) * KP + kg * 8];
  const unsigned short* wb = &Wl[(wc * 64 + l15) * KP + kg * 8];

#pragma unroll
  for (int k0 = 0; k0 < K; k0 += 32) {
    f16x8 af = *(const f16x8*)(xa + k0);
#pragma unroll
    for (int t = 0; t < 4; t++) {
      f16x8 bf = *(const f16x8*)(wb + t * 16 * KP + k0);
      acc[t] = __builtin_amdgcn_mfma_f32_16x16x32_f16(af, bf, acc[t], 0, 0, 0);
    }
  }

  // epilogue: bias (+wvec*bias2), store Y, BN stats
  int rbase = rowBlk + wr * 16 + 4 * kg;
  float wrow[4];
#pragma unroll
  for (int r = 0; r < 4; r++)
    wrow[r] = (wvec && rbase + r < N) ? wvec[rbase + r] : 0.f;

#pragma unroll
  for (int t = 0; t < 4; t++) {
    int ch = wc * 64 + t * 16 + l15;
    float bb = bias[ch];
    float b2 = bias2 ? bias2[ch] : 0.f;
    float s = 0.f, q = 0.f;
#pragma unroll
    for (int r = 0; r < 4; r++) {
      int row = rbase + r;
      if (row < N) {
        float o = acc[t][r] + bb;
        if (wvec) o = fmaf(wrow[r], b2, o);
        Y[(size_t)row * 128 + ch] = o;
        s += o;
        q += o * o;
      }
    }
    s += __shfl_xor(s, 16); s += __shfl_xor(s, 32);
    q += __shfl_xor(q, 16); q += __shfl_xor(q, 32);
    if (kg == 0) { red[wr][0][ch] = s; red[wr][1][ch] = q; }
  }
  __syncthreads();
  int t2 = threadIdx.x;
  int st = t2 >> 7, ch = t2 & 127;
  atomicAdd(&stat[st * 128 + ch], red[0][st][ch] + red[1][st][ch]);
}

__global__ __launch_bounds__(128) void k_bnfinal(const float* __restrict__ stat,
                                                 const float* __restrict__ gamma,
                                                 const float* __restrict__ beta,
                                                 float invN,
                                                 float* __restrict__ scsh) {
  int c = threadIdx.x;
  float mu = stat[c] * invN;
  float var = stat[128 + c] * invN - mu * mu;
  float sc = rsqrtf(var + 1e-5f) * gamma[c];
  scsh[c] = sc;
  scsh[128 + c] = beta[c] - mu * sc;
}

// ---- Pool (fused BN+ReLU of last layer) ----
__global__ __launch_bounds__(128) void k_gstart(const int* __restrict__ batch, int N,
                                                int* __restrict__ gstart) {
  int g = threadIdx.x;
  if (g <= 64) {
    int lo = 0, hi = N;
    while (lo < hi) {
      int mid = (lo + hi) >> 1;
      if (batch[mid] < g) lo = mid + 1;
      else hi = mid;
    }
    gstart[g] = lo;   // lower_bound; gstart[64] == N
  }
}

__global__ __launch_bounds__(128) void k_pool(const float* __restrict__ H,
                                              const float* __restrict__ scsh,
                                              const int* __restrict__ gstart,
                                              float* __restrict__ pooled) {
  int g = blockIdx.x >> 3;
  int part = blockIdx.x & 7;
  int c = threadIdx.x;
  float sc = scsh[c], sh = scsh[128 + c];
  int beg = gstart[g], end = gstart[g + 1];
  int len = end - beg;
  int pbeg = beg + (len * part) / 8;
  int pend = beg + (len * (part + 1)) / 8;
  float s = 0.f;
  for (int r = pbeg; r < pend; r++) {
    float v = H[(size_t)r * 128 + c];
    s += fmaxf(fmaf(v, sc, sh), 0.f);
  }
  atomicAdd(&pooled[g * 128 + c], s);
}

// ---- Head MLP ----
__global__ __launch_bounds__(256) void k_mlp(const float* __restrict__ pooled,
                                             const int* __restrict__ gstart,
                                             const float* __restrict__ W1,
                                             const float* __restrict__ b1,
                                             const float* __restrict__ W2,
                                             const float* __restrict__ b2,
                                             float* __restrict__ out) {
  __shared__ float P[64 * 128];
  __shared__ float Z[64 * 64];
  for (int i = threadIdx.x; i < 64 * 128; i += 256) {
    int g = i >> 7;
    int cnt = gstart[g + 1] - gstart[g];
    P[i] = pooled[i] / (float)(cnt > 1 ? cnt : 1);
  }
  __syncthreads();
  for (int i = threadIdx.x; i < 64 * 64; i += 256) {
    int g = i >> 6, m = i & 63;
    float acc = b1[m];
    for (int k = 0; k < 128; k++) acc += P[(g << 7) + k] * W1[k * 64 + m];
    Z[i] = fmaxf(acc, 0.f);
  }
  __syncthreads();
  if (threadIdx.x < 64) {
    int g = threadIdx.x;
    float acc = b2[0];
    for (int m = 0; m < 64; m++) acc += Z[(g << 6) + m] * W2[m];
    out[g] = 1.f / (1.f + expf(-acc));
  }
}

// ---------------------------------------------------------------------------

extern "C" void kernel_launch(void* const* d_in, const int* in_sizes, int n_in,
                              void* d_out, int out_size, void* d_ws, size_t ws_size,
                              hipStream_t stream) {
  const float* x      = (const float*)d_in[0];
  const int*   ei     = (const int*)d_in[1];
  const int*   batch  = (const int*)d_in[2];
  const float* W_enc  = (const float*)d_in[3];
  const float* b_enc  = (const float*)d_in[4];
  const float* Wc     = (const float*)d_in[5];
  const float* bc     = (const float*)d_in[6];
  const float* gamma  = (const float*)d_in[7];
  const float* beta   = (const float*)d_in[8];
  const float* W1     = (const float*)d_in[9];
  const float* b1     = (const float*)d_in[10];
  const float* W2     = (const float*)d_in[11];
  const float* b2     = (const float*)d_in[12];
  float* out = (float*)d_out;

  const int N = in_sizes[2];         // 50000
  const int E = in_sizes[1] / 2;     // 500000
  const int NL = in_sizes[6] / 128;  // 2 layers

  size_t off = 0;
  auto alloc = [&](size_t bytes) {
    void* p = (char*)d_ws + off;
    off += (bytes + 255) & ~(size_t)255;
    return p;
  };
  float* bufA   = (float*)alloc((size_t)N * 128 * 4);     // h (fp32)
  int*   deg    = (int*)alloc((size_t)N * 4);
  float* dinv   = (float*)alloc((size_t)N * 4);
  int*   rowptr = (int*)alloc((size_t)(N + 1) * 4);
  int*   cursor = (int*)alloc((size_t)N * 4);
  int*   colx   = (int*)alloc((size_t)(E + N) * 4);
  int*   blksum = (int*)alloc(1024 * 4);
  float* bnstat = (float*)alloc(512 * 4);
  float* scsh   = (float*)alloc(512 * 4);
  float* pooled = (float*)alloc(64 * 128 * 4);
  int*   gstart = (int*)alloc(65 * 4);
  unsigned short* MT  = (unsigned short*)alloc(128 * 64 * 2);   // fp16 (W_enc@Wc0)^T
  unsigned short* WT1 = (unsigned short*)alloc(128 * 128 * 2);  // fp16 Wc[l]^T
  float* bfold  = (float*)alloc(128 * 4);
  unsigned* xs  = (unsigned*)alloc((size_t)N * 64 * 2);    // fp16 x*dinv
  unsigned* hs  = (unsigned*)alloc((size_t)N * 128 * 2);   // fp16 BNReLU(h)*dinv
  unsigned* axh = (unsigned*)alloc((size_t)N * 64 * 2);    // fp16 agg0 out
  uint2*    a1h = (uint2*)alloc((size_t)N * 128 * 2);      // fp16 agg1 out
  float* wv     = (float*)alloc((size_t)N * 4);

  int nbN = (N + 255) / 256;

  k_init<<<nbN, 256, 0, stream>>>(deg, pooled, bnstat, N);
  k_deg<<<(E + 255) / 256, 256, 0, stream>>>(ei, E, deg);
  k_scan_a<<<nbN, 256, 0, stream>>>(deg, N, rowptr, blksum);
  k_scan_b<<<1, 256, 0, stream>>>(blksum, nbN);
  k_scan_c<<<(N + 1 + 255) / 256, 256, 0, stream>>>(deg, N, E + N, blksum,
                                                    rowptr, cursor, dinv);
  k_fill<<<(E + N + 255) / 256, 256, 0, stream>>>(ei, E, N, cursor, colx);
  k_fold<<<65, 128, 0, stream>>>(W_enc, b_enc, Wc, MT, bfold);

  int gemmGrid = (N + 31) / 32;

  // ---- layer 0: agg(x) -> MFMA GEMM (encoder folded) ----
  k_prep0<<<(N * 16 + 255) / 256, 256, 0, stream>>>(x, dinv, xs, N * 16);
  k_agg0<<<2048, 256, 0, stream>>>(xs, rowptr, colx, dinv, axh, wv, N);
  k_gemm_f16<64><<<gemmGrid, 256, 0, stream>>>(
      (const unsigned short*)axh, MT, bc, wv, bfold, bnstat, bufA, N);
  k_bnfinal<<<1, 128, 0, stream>>>(bnstat, gamma, beta, 1.f / (float)N, scsh);

  // ---- layers 1..NL-1 ----
  for (int l = 1; l < NL; l++) {
    k_wprep<<<64, 256, 0, stream>>>(Wc + (size_t)l * 128 * 128, WT1);
    k_prep1<<<(N * 32 + 255) / 256, 256, 0, stream>>>(
        bufA, scsh + (l - 1) * 256, dinv, hs, N * 32);
    k_agg1<<<2048, 256, 0, stream>>>((const uint2*)hs, rowptr, colx, dinv,
                                     a1h, N);
    k_gemm_f16<128><<<gemmGrid, 256, 0, stream>>>(
        (const unsigned short*)a1h, WT1, bc + l * 128, nullptr, nullptr,
        bnstat + l * 256, bufA, N);
    k_bnfinal<<<1, 128, 0, stream>>>(bnstat + l * 256, gamma + l * 128,
                                     beta + l * 128, 1.f / (float)N,
                                     scsh + l * 256);
  }

  k_gstart<<<1, 128, 0, stream>>>(batch, N, gstart);
  k_pool<<<64 * 8, 128, 0, stream>>>(bufA, scsh + (NL - 1) * 256, gstart, pooled);
  k_mlp<<<1, 256, 0, stream>>>(pooled, gstart, W1, b1, W2, b2, out);
}

// Round 8
// 295.100 us; speedup vs baseline: 1.5253x; 1.2451x over previous
//
#include <hip/hip_runtime.h>
#include <hip/hip_bf16.h>
#include <hip/hip_fp16.h>
#include <math.h>

// ---------------------------------------------------------------------------
// GCN forward on MI355X. fp16 gather tables + fp16 MFMA GEMMs (fp32 accum).
// Structure (R5): aggregate FIRST (linear), GEMM after:
//   l0: ax = dinv_d*sum(dinv_s*x_s) ; h1 = ax@M + w_d*bfold + bc0   [MFMA K=64]
//   l1: a1 = dinv_d*sum(dinv_s*BNReLU(h1)_s); h2 = a1@Wc1 + bc1     [MFMA K=128]
//   pool(BN+ReLU fused) -> MLP -> sigmoid
// Lessons:
//   R5: gather is past-L2-BW bound -> fp16 tables, aggregate-first.
//   R6: fp32 VALU GEMM dead end -> MFMA.
//   R7: per-tile W+X LDS staging & 2 barriers at 32-row tiles left MFMA
//       util at 1% and 51us -> W staged ONCE per 64-row block, A-frags
//       direct from global, h stored fp16, stat atomics x8 replicas.
// ---------------------------------------------------------------------------

typedef _Float16 f16x8 __attribute__((ext_vector_type(8)));
typedef float f32x4 __attribute__((ext_vector_type(4)));

__device__ inline unsigned pack2(float a, float b) {
  union { __half2 h; unsigned u; } p;
  p.h = __floats2half2_rn(a, b);
  return p.u;
}
__device__ inline float2 unpack2(unsigned u) {
  union { unsigned u; __half2 h; } p;
  p.u = u;
  return __half22float2(p.h);
}

__global__ __launch_bounds__(256) void k_init(int* __restrict__ deg,
                                              float* __restrict__ pooled,
                                              float* __restrict__ bnstat,
                                              int N) {
  int i = blockIdx.x * 256 + threadIdx.x;
  if (i < N) deg[i] = 1;           // self-loop
  if (i < 64 * 128) pooled[i] = 0.f;
  if (i < 4096) bnstat[i] = 0.f;   // 2 layers x 8 replicas x (sum,sumsq)[128]
}

__global__ __launch_bounds__(256) void k_deg(const int* __restrict__ ei, int E,
                                             int* __restrict__ deg) {
  int i = blockIdx.x * 256 + threadIdx.x;
  if (i < E) atomicAdd(&deg[ei[E + i]], 1);   // dst row
}

// ---- 3-kernel exclusive scan over deg[N] -> rowptr ----
__global__ __launch_bounds__(256) void k_scan_a(const int* __restrict__ deg, int N,
                                                int* __restrict__ rowptr,
                                                int* __restrict__ blksum) {
  __shared__ int s[256];
  int t = threadIdx.x;
  int i = blockIdx.x * 256 + t;
  int v = (i < N) ? deg[i] : 0;
  s[t] = v;
  __syncthreads();
  for (int off = 1; off < 256; off <<= 1) {
    int x = (t >= off) ? s[t - off] : 0;
    __syncthreads();
    s[t] += x;
    __syncthreads();
  }
  if (i < N) rowptr[i] = s[t] - v;            // exclusive (partial)
  if (t == 255) blksum[blockIdx.x] = s[255];
}

__global__ __launch_bounds__(256) void k_scan_b(int* __restrict__ blksum, int nb) {
  __shared__ int s[256];
  int t = threadIdx.x;
  int v = (t < nb) ? blksum[t] : 0;
  s[t] = v;
  __syncthreads();
  for (int off = 1; off < 256; off <<= 1) {
    int x = (t >= off) ? s[t - off] : 0;
    __syncthreads();
    s[t] += x;
    __syncthreads();
  }
  if (t < nb) blksum[t] = s[t] - v;           // exclusive
}

__global__ __launch_bounds__(256) void k_scan_c(const int* __restrict__ deg, int N,
                                                int total,
                                                const int* __restrict__ blksum,
                                                int* __restrict__ rowptr,
                                                int* __restrict__ cursor,
                                                float* __restrict__ dinv) {
  int i = blockIdx.x * 256 + threadIdx.x;
  if (i < N) {
    int rp = rowptr[i] + blksum[blockIdx.x];
    rowptr[i] = rp;
    cursor[i] = rp;
    dinv[i] = rsqrtf((float)deg[i]);
  } else if (i == N) {
    rowptr[N] = total;
  }
}

__global__ __launch_bounds__(256) void k_fill(const int* __restrict__ ei, int E, int N,
                                              int* __restrict__ cursor,
                                              int* __restrict__ colx) {
  int i = blockIdx.x * 256 + threadIdx.x;
  if (i < E) {
    int s = ei[i];
    int d = ei[E + i];
    int pos = atomicAdd(&cursor[d], 1);
    colx[pos] = s;
  } else if (i < E + N) {
    int j = i - E;
    int pos = atomicAdd(&cursor[j], 1);
    colx[pos] = j;                           // self-loop entry
  }
}

// ---- Fold encoder: MT[n][k] = fp16((W_enc @ Wc0)[k][n]); bfold = b_enc @ Wc0
__global__ __launch_bounds__(128) void k_fold(const float* __restrict__ W_enc,
                                              const float* __restrict__ b_enc,
                                              const float* __restrict__ Wc0,
                                              unsigned short* __restrict__ MT,
                                              float* __restrict__ bfold) {
  int n = threadIdx.x;                 // 0..127
  int k = blockIdx.x;                  // 0..64 (64 == bias row)
  const float* arow = (k < 64) ? (W_enc + (size_t)k * 128) : b_enc;
  float acc = 0.f;
  for (int j = 0; j < 128; j++) acc = fmaf(arow[j], Wc0[(size_t)j * 128 + n], acc);
  if (k < 64) ((__half*)MT)[(size_t)n * 64 + k] = __float2half(acc);
  else bfold[n] = acc;
}

// ---- transpose+cast a 128x128 fp32 W into fp16 WT[n][k] ----
__global__ __launch_bounds__(256) void k_wprep(const float* __restrict__ Wsrc,
                                               unsigned short* __restrict__ WT) {
  int i = blockIdx.x * 256 + threadIdx.x;   // 16384
  int n = i & 127, k = i >> 7;              // coalesced read
  ((__half*)WT)[(size_t)n * 128 + k] = __float2half(Wsrc[i]);
}

// ---- prep0: xs[row][64] fp16 = x[row] * dinv[row] ----
__global__ __launch_bounds__(256) void k_prep0(const float* __restrict__ x,
                                               const float* __restrict__ dinv,
                                               unsigned* __restrict__ xs2,
                                               int total /* N*16 */) {
  int i = blockIdx.x * 256 + threadIdx.x;
  if (i < total) {
    int row = i >> 4;
    float4 v = ((const float4*)x)[i];
    float d = dinv[row];
    uint2 o;
    o.x = pack2(v.x * d, v.y * d);
    o.y = pack2(v.z * d, v.w * d);
    ((uint2*)xs2)[i] = o;
  }
}

// ---- prep1: hs[row][128] fp16 = relu(h16*sc+sh) * dinv[row] ----
__global__ __launch_bounds__(256) void k_prep1(const unsigned short* __restrict__ H16,
                                               const float* __restrict__ scsh,
                                               const float* __restrict__ dinv,
                                               unsigned* __restrict__ hs2,
                                               int total /* N*32 */) {
  int i = blockIdx.x * 256 + threadIdx.x;
  if (i < total) {
    int row = i >> 5;
    int c4 = i & 31;
    uint2 hv = ((const uint2*)H16)[i];
    float2 h01 = unpack2(hv.x), h23 = unpack2(hv.y);
    float4 sc = ((const float4*)scsh)[c4];
    float4 sh = ((const float4*)(scsh + 128))[c4];
    float d = dinv[row];
    float a = fmaxf(fmaf(h01.x, sc.x, sh.x), 0.f) * d;
    float b = fmaxf(fmaf(h01.y, sc.y, sh.y), 0.f) * d;
    float c = fmaxf(fmaf(h23.x, sc.z, sh.z), 0.f) * d;
    float e = fmaxf(fmaf(h23.y, sc.w, sh.w), 0.f) * d;
    uint2 o;
    o.x = pack2(a, b);
    o.y = pack2(c, e);
    ((uint2*)hs2)[i] = o;
  }
}

// ---- agg0: axh[i][64] fp16 = dinv_i * sum xs[s]; w[i] = dinv_i * sum dinv_s
__global__ __launch_bounds__(256) void k_agg0(const unsigned* __restrict__ xs,
                                              const int* __restrict__ rowptr,
                                              const int* __restrict__ colx,
                                              const float* __restrict__ dinv,
                                              unsigned* __restrict__ axh,
                                              float* __restrict__ w, int N) {
  int lane = threadIdx.x & 63;
  int wv = threadIdx.x >> 6;
  int half = lane >> 5;
  int l32 = lane & 31;
  int wid = blockIdx.x * 4 + wv;
  int nw = gridDim.x * 4;

  for (int base = 2 * wid; base < N; base += 2 * nw) {
    int i = base + half;
    if (i < N) {
      int beg = rowptr[i];
      int end = rowptr[i + 1];
      float sx = 0.f, sy = 0.f, sd = 0.f;
      int e = beg;
#pragma unroll 1
      for (; e + 4 <= end; e += 4) {
        int i0 = colx[e + 0], i1 = colx[e + 1], i2 = colx[e + 2], i3 = colx[e + 3];
        unsigned v0 = xs[(size_t)i0 * 32 + l32];
        unsigned v1 = xs[(size_t)i1 * 32 + l32];
        unsigned v2 = xs[(size_t)i2 * 32 + l32];
        unsigned v3 = xs[(size_t)i3 * 32 + l32];
        float d0 = dinv[i0], d1 = dinv[i1], d2 = dinv[i2], d3 = dinv[i3];
        float2 f0 = unpack2(v0), f1 = unpack2(v1), f2 = unpack2(v2), f3 = unpack2(v3);
        sx += (f0.x + f1.x) + (f2.x + f3.x);
        sy += (f0.y + f1.y) + (f2.y + f3.y);
        sd += (d0 + d1) + (d2 + d3);
      }
#pragma unroll 1
      for (; e < end; e++) {
        int sr = colx[e];
        float2 f = unpack2(xs[(size_t)sr * 32 + l32]);
        sx += f.x;
        sy += f.y;
        sd += dinv[sr];
      }
      float di = dinv[i];
      axh[(size_t)i * 32 + l32] = pack2(sx * di, sy * di);
      if (l32 == 0) w[i] = di * sd;
    }
  }
}

// ---- agg1: a1h[i][128] fp16 = dinv_i * sum hs[s] ----
__global__ __launch_bounds__(256) void k_agg1(const uint2* __restrict__ hs,
                                              const int* __restrict__ rowptr,
                                              const int* __restrict__ colx,
                                              const float* __restrict__ dinv,
                                              uint2* __restrict__ a1h, int N) {
  int lane = threadIdx.x & 63;
  int wv = threadIdx.x >> 6;
  int half = lane >> 5;
  int l32 = lane & 31;
  int wid = blockIdx.x * 4 + wv;
  int nw = gridDim.x * 4;

  for (int base = 2 * wid; base < N; base += 2 * nw) {
    int i = base + half;
    if (i < N) {
      int beg = rowptr[i];
      int end = rowptr[i + 1];
      float4 s = make_float4(0.f, 0.f, 0.f, 0.f);
      int e = beg;
#pragma unroll 1
      for (; e + 4 <= end; e += 4) {
        int i0 = colx[e + 0], i1 = colx[e + 1], i2 = colx[e + 2], i3 = colx[e + 3];
        uint2 v0 = hs[(size_t)i0 * 32 + l32];
        uint2 v1 = hs[(size_t)i1 * 32 + l32];
        uint2 v2 = hs[(size_t)i2 * 32 + l32];
        uint2 v3 = hs[(size_t)i3 * 32 + l32];
        float2 a0 = unpack2(v0.x), b0 = unpack2(v0.y);
        float2 a1f = unpack2(v1.x), b1f = unpack2(v1.y);
        float2 a2 = unpack2(v2.x), b2 = unpack2(v2.y);
        float2 a3 = unpack2(v3.x), b3 = unpack2(v3.y);
        s.x += (a0.x + a1f.x) + (a2.x + a3.x);
        s.y += (a0.y + a1f.y) + (a2.y + a3.y);
        s.z += (b0.x + b1f.x) + (b2.x + b3.x);
        s.w += (b0.y + b1f.y) + (b2.y + b3.y);
      }
#pragma unroll 1
      for (; e < end; e++) {
        int sr = colx[e];
        uint2 v = hs[(size_t)sr * 32 + l32];
        float2 a = unpack2(v.x), b = unpack2(v.y);
        s.x += a.x; s.y += a.y; s.z += b.x; s.w += b.y;
      }
      float di = dinv[i];
      a1h[(size_t)i * 32 + l32] =
          make_uint2(pack2(s.x * di, s.y * di), pack2(s.z * di, s.w * di));
    }
  }
}

// ---- MFMA GEMM: Yh[N][128] fp16 = Xh[N][K](fp16) @ WT(fp16,[n][k]) + bias
//                 (+ wvec[row]*bias2[col]) ; fused BN stats (8 replicas).
// Block = 64 rows, 4 waves; wave = 16 rows x 128 cols (8 MFMA col-groups).
// W staged ONCE into LDS; A-fragments read straight from global (each wave's
// 4x b128 covers a dense 16-row window; X read exactly once). One barrier
// after W-stage; no per-tile barriers (R7).
// A-frag: row=lane&15, k=(lane>>4)*8+i. C/D: row=(lane>>4)*4+reg, col=lane&15.
template <int K>
__global__ __launch_bounds__(256, 2) void k_gemm_f16(
    const unsigned short* __restrict__ Xh,   // N x K fp16
    const unsigned short* __restrict__ WT,   // 128 x K fp16 (n-major)
    const float* __restrict__ bias,          // [128]
    const float* __restrict__ wvec,          // [N] or null (layer0)
    const float* __restrict__ bias2,         // [128] or null (layer0)
    float* __restrict__ stat,                // 8 x [256] replicas
    unsigned short* __restrict__ Yh,         // N x 128 fp16 out
    int N) {
  constexpr int KP = K + 8;
  constexpr int K8 = K / 8;
  __shared__ unsigned short Wl[128 * KP];
  __shared__ float red[4][2][128];

  for (int i = threadIdx.x; i < 128 * K8; i += 256) {
    int r = i / K8, c = i - r * K8;
    *(uint4*)&Wl[r * KP + c * 8] = ((const uint4*)(WT + (size_t)r * K))[c];
  }
  __syncthreads();

  int lane = threadIdx.x & 63;
  int wv = threadIdx.x >> 6;
  int l15 = lane & 15;
  int kg = lane >> 4;            // k-group 0..3
  int tileRow = blockIdx.x * 64 + wv * 16;

  // A-fragments straight from global (row = l15 within the wave's 16 rows)
  int arow = tileRow + l15;
  if (arow >= N) arow = N - 1;   // clamp; stores/stats guarded below
  const unsigned short* xp = Xh + (size_t)arow * K + kg * 8;
  f16x8 af[K / 32];
#pragma unroll
  for (int j = 0; j < K / 32; j++) af[j] = *(const f16x8*)(xp + j * 32);

  f32x4 acc[8];
#pragma unroll
  for (int t = 0; t < 8; t++) acc[t] = {0.f, 0.f, 0.f, 0.f};

  const unsigned short* wb = &Wl[l15 * KP + kg * 8];
#pragma unroll
  for (int j = 0; j < K / 32; j++) {
#pragma unroll
    for (int t = 0; t < 8; t++) {
      f16x8 bf = *(const f16x8*)(wb + t * 16 * KP + j * 32);
      acc[t] = __builtin_amdgcn_mfma_f32_16x16x32_f16(af[j], bf, acc[t], 0, 0, 0);
    }
  }

  // epilogue: bias (+wvec*bias2), fp16 store, BN stats
  int rbase = tileRow + kg * 4;
  float wrow[4];
#pragma unroll
  for (int r = 0; r < 4; r++)
    wrow[r] = (wvec && rbase + r < N) ? wvec[rbase + r] : 0.f;

#pragma unroll
  for (int t = 0; t < 8; t++) {
    int ch = t * 16 + l15;
    float bb = bias[ch];
    float b2v = bias2 ? bias2[ch] : 0.f;
    float s = 0.f, q = 0.f;
#pragma unroll
    for (int r = 0; r < 4; r++) {
      int row = rbase + r;
      if (row < N) {
        float o = acc[t][r] + bb;
        if (wvec) o = fmaf(wrow[r], b2v, o);
        __half oh = __float2half(o);
        Yh[(size_t)row * 128 + ch] = *(unsigned short*)&oh;
        s += o;
        q += o * o;
      }
    }
    s += __shfl_xor(s, 16); s += __shfl_xor(s, 32);
    q += __shfl_xor(q, 16); q += __shfl_xor(q, 32);
    if (kg == 0) { red[wv][0][ch] = s; red[wv][1][ch] = q; }
  }
  __syncthreads();
  int st = threadIdx.x >> 7, ch2 = threadIdx.x & 127;
  float v = red[0][st][ch2] + red[1][st][ch2] + red[2][st][ch2] + red[3][st][ch2];
  atomicAdd(&stat[(blockIdx.x & 7) * 256 + st * 128 + ch2], v);
}

__global__ __launch_bounds__(128) void k_bnfinal(const float* __restrict__ stat,
                                                 const float* __restrict__ gamma,
                                                 const float* __restrict__ beta,
                                                 float invN,
                                                 float* __restrict__ scsh) {
  int c = threadIdx.x;
  float ssum = 0.f, qsum = 0.f;
#pragma unroll
  for (int rep = 0; rep < 8; rep++) {
    ssum += stat[rep * 256 + c];
    qsum += stat[rep * 256 + 128 + c];
  }
  float mu = ssum * invN;
  float var = qsum * invN - mu * mu;
  float sc = rsqrtf(var + 1e-5f) * gamma[c];
  scsh[c] = sc;
  scsh[128 + c] = beta[c] - mu * sc;
}

// ---- Pool (fused BN+ReLU of last layer; h2 is fp16) ----
__global__ __launch_bounds__(128) void k_gstart(const int* __restrict__ batch, int N,
                                                int* __restrict__ gstart) {
  int g = threadIdx.x;
  if (g <= 64) {
    int lo = 0, hi = N;
    while (lo < hi) {
      int mid = (lo + hi) >> 1;
      if (batch[mid] < g) lo = mid + 1;
      else hi = mid;
    }
    gstart[g] = lo;   // lower_bound; gstart[64] == N
  }
}

__global__ __launch_bounds__(128) void k_pool(const unsigned short* __restrict__ H16,
                                              const float* __restrict__ scsh,
                                              const int* __restrict__ gstart,
                                              float* __restrict__ pooled) {
  int g = blockIdx.x >> 3;
  int part = blockIdx.x & 7;
  int c = threadIdx.x;
  float sc = scsh[c], sh = scsh[128 + c];
  int beg = gstart[g], end = gstart[g + 1];
  int len = end - beg;
  int pbeg = beg + (len * part) / 8;
  int pend = beg + (len * (part + 1)) / 8;
  float s = 0.f;
  for (int r = pbeg; r < pend; r++) {
    float v = __half2float(((const __half*)H16)[(size_t)r * 128 + c]);
    s += fmaxf(fmaf(v, sc, sh), 0.f);
  }
  atomicAdd(&pooled[g * 128 + c], s);
}

// ---- Head MLP ----
__global__ __launch_bounds__(256) void k_mlp(const float* __restrict__ pooled,
                                             const int* __restrict__ gstart,
                                             const float* __restrict__ W1,
                                             const float* __restrict__ b1,
                                             const float* __restrict__ W2,
                                             const float* __restrict__ b2,
                                             float* __restrict__ out) {
  __shared__ float P[64 * 128];
  __shared__ float Z[64 * 64];
  for (int i = threadIdx.x; i < 64 * 128; i += 256) {
    int g = i >> 7;
    int cnt = gstart[g + 1] - gstart[g];
    P[i] = pooled[i] / (float)(cnt > 1 ? cnt : 1);
  }
  __syncthreads();
  for (int i = threadIdx.x; i < 64 * 64; i += 256) {
    int g = i >> 6, m = i & 63;
    float acc = b1[m];
    for (int k = 0; k < 128; k++) acc += P[(g << 7) + k] * W1[k * 64 + m];
    Z[i] = fmaxf(acc, 0.f);
  }
  __syncthreads();
  if (threadIdx.x < 64) {
    int g = threadIdx.x;
    float acc = b2[0];
    for (int m = 0; m < 64; m++) acc += Z[(g << 6) + m] * W2[m];
    out[g] = 1.f / (1.f + expf(-acc));
  }
}

// ---------------------------------------------------------------------------

extern "C" void kernel_launch(void* const* d_in, const int* in_sizes, int n_in,
                              void* d_out, int out_size, void* d_ws, size_t ws_size,
                              hipStream_t stream) {
  const float* x      = (const float*)d_in[0];
  const int*   ei     = (const int*)d_in[1];
  const int*   batch  = (const int*)d_in[2];
  const float* W_enc  = (const float*)d_in[3];
  const float* b_enc  = (const float*)d_in[4];
  const float* Wc     = (const float*)d_in[5];
  const float* bc     = (const float*)d_in[6];
  const float* gamma  = (const float*)d_in[7];
  const float* beta   = (const float*)d_in[8];
  const float* W1     = (const float*)d_in[9];
  const float* b1     = (const float*)d_in[10];
  const float* W2     = (const float*)d_in[11];
  const float* b2     = (const float*)d_in[12];
  float* out = (float*)d_out;

  const int N = in_sizes[2];         // 50000
  const int E = in_sizes[1] / 2;     // 500000
  const int NL = in_sizes[6] / 128;  // 2 layers

  size_t off = 0;
  auto alloc = [&](size_t bytes) {
    void* p = (char*)d_ws + off;
    off += (bytes + 255) & ~(size_t)255;
    return p;
  };
  unsigned short* h16 = (unsigned short*)alloc((size_t)N * 128 * 2);  // h fp16
  int*   deg    = (int*)alloc((size_t)N * 4);
  float* dinv   = (float*)alloc((size_t)N * 4);
  int*   rowptr = (int*)alloc((size_t)(N + 1) * 4);
  int*   cursor = (int*)alloc((size_t)N * 4);
  int*   colx   = (int*)alloc((size_t)(E + N) * 4);
  int*   blksum = (int*)alloc(1024 * 4);
  float* bnstat = (float*)alloc(4096 * 4);  // 2 layers x 8 reps x 256
  float* scsh   = (float*)alloc(512 * 4);
  float* pooled = (float*)alloc(64 * 128 * 4);
  int*   gstart = (int*)alloc(65 * 4);
  unsigned short* MT  = (unsigned short*)alloc(128 * 64 * 2);   // fp16 (W_enc@Wc0)^T
  unsigned short* WT1 = (unsigned short*)alloc(128 * 128 * 2);  // fp16 Wc[l]^T
  float* bfold  = (float*)alloc(128 * 4);
  unsigned* xs  = (unsigned*)alloc((size_t)N * 64 * 2);    // fp16 x*dinv
  unsigned* hs  = (unsigned*)alloc((size_t)N * 128 * 2);   // fp16 BNReLU(h)*dinv
  unsigned* axh = (unsigned*)alloc((size_t)N * 64 * 2);    // fp16 agg0 out
  uint2*    a1h = (uint2*)alloc((size_t)N * 128 * 2);      // fp16 agg1 out
  float* wv     = (float*)alloc((size_t)N * 4);

  int nbN = (N + 255) / 256;

  k_init<<<nbN, 256, 0, stream>>>(deg, pooled, bnstat, N);
  k_deg<<<(E + 255) / 256, 256, 0, stream>>>(ei, E, deg);
  k_scan_a<<<nbN, 256, 0, stream>>>(deg, N, rowptr, blksum);
  k_scan_b<<<1, 256, 0, stream>>>(blksum, nbN);
  k_scan_c<<<(N + 1 + 255) / 256, 256, 0, stream>>>(deg, N, E + N, blksum,
                                                    rowptr, cursor, dinv);
  k_fill<<<(E + N + 255) / 256, 256, 0, stream>>>(ei, E, N, cursor, colx);
  k_fold<<<65, 128, 0, stream>>>(W_enc, b_enc, Wc, MT, bfold);

  int tiles = (N + 63) / 64;

  // ---- layer 0: agg(x) -> MFMA GEMM (encoder folded) ----
  k_prep0<<<(N * 16 + 255) / 256, 256, 0, stream>>>(x, dinv, xs, N * 16);
  k_agg0<<<2048, 256, 0, stream>>>(xs, rowptr, colx, dinv, axh, wv, N);
  k_gemm_f16<64><<<tiles, 256, 0, stream>>>(
      (const unsigned short*)axh, MT, bc, wv, bfold, bnstat, h16, N);
  k_bnfinal<<<1, 128, 0, stream>>>(bnstat, gamma, beta, 1.f / (float)N, scsh);

  // ---- layers 1..NL-1 ----
  for (int l = 1; l < NL; l++) {
    k_wprep<<<64, 256, 0, stream>>>(Wc + (size_t)l * 128 * 128, WT1);
    k_prep1<<<(N * 32 + 255) / 256, 256, 0, stream>>>(
        h16, scsh + (l - 1) * 256, dinv, hs, N * 32);
    k_agg1<<<2048, 256, 0, stream>>>((const uint2*)hs, rowptr, colx, dinv,
                                     a1h, N);
    k_gemm_f16<128><<<tiles, 256, 0, stream>>>(
        (const unsigned short*)a1h, WT1, bc + l * 128, nullptr, nullptr,
        bnstat + l * 2048, h16, N);
    k_bnfinal<<<1, 128, 0, stream>>>(bnstat + l * 2048, gamma + l * 128,
                                     beta + l * 128, 1.f / (float)N,
                                     scsh + l * 256);
  }

  k_gstart<<<1, 128, 0, stream>>>(batch, N, gstart);
  k_pool<<<64 * 8, 128, 0, stream>>>(h16, scsh + (NL - 1) * 256, gstart, pooled);
  k_mlp<<<1, 256, 0, stream>>>(pooled, gstart, W1, b1, W2, b2, out);
}

// Round 9
// 277.970 us; speedup vs baseline: 1.6193x; 1.0616x over previous
//
#include <hip/hip_runtime.h>
#include <hip/hip_bf16.h>
#include <hip/hip_fp16.h>
#include <math.h>

// ---------------------------------------------------------------------------
// GCN forward on MI355X. fp16 gather tables + fp16 MFMA GEMMs (fp32 accum).
// Structure (R5): aggregate FIRST (linear), GEMM after:
//   l0: ax = dinv_d*sum(dinv_s*x_s) ; h1 = ax@M + w_d*bfold + bc0   [MFMA K=64]
//   l1: a1 = dinv_d*sum(dinv_s*BNReLU(h1)_s); h2 = a1@Wc1 + bc1     [MFMA K=128]
//   pool(BN+ReLU fused) -> MLP -> sigmoid
// Lessons:
//   R5: gather is past-L2-BW bound -> fp16 tables, aggregate-first.
//   R6: fp32 VALU GEMM dead end -> MFMA.
//   R7: W staged once/block, A-frags from global, fp16 h, stat replicas x8.
//   R8: no dominant kernel left; 19 serial dispatches -> 13 (setup fusion,
//       fill+prep0 fusion, bnfinal inlined into prep1/pool); agg0 quarter-wave.
// ---------------------------------------------------------------------------

typedef _Float16 f16x8 __attribute__((ext_vector_type(8)));
typedef float f32x4 __attribute__((ext_vector_type(4)));

__device__ inline unsigned pack2(float a, float b) {
  union { __half2 h; unsigned u; } p;
  p.h = __floats2half2_rn(a, b);
  return p.u;
}
__device__ inline float2 unpack2(unsigned u) {
  union { unsigned u; __half2 h; } p;
  p.u = u;
  return __half22float2(p.h);
}

// ---- setup: deg=1 / pooled=0 / bnstat=0  +  encoder fold  +  W1 transpose
//      + per-graph boundary search. All independent; one dispatch. ----
__global__ __launch_bounds__(256) void k_setup(
    int* __restrict__ deg, float* __restrict__ pooled,
    float* __restrict__ bnstat, int statTotal, int N, int nbN,
    const float* __restrict__ W_enc, const float* __restrict__ b_enc,
    const float* __restrict__ Wc, unsigned short* __restrict__ MT,
    float* __restrict__ bfold, int NL,
    const float* __restrict__ Wc1, unsigned short* __restrict__ WT1,
    const int* __restrict__ batch, int* __restrict__ gstart) {
  int b = blockIdx.x;
  if (b < nbN) {                       // init
    int i = b * 256 + threadIdx.x;
    if (i < N) deg[i] = 1;             // self-loop
    if (i < 64 * 128) pooled[i] = 0.f;
    if (i < statTotal) bnstat[i] = 0.f;
    return;
  }
  b -= nbN;
  if (b < 65) {                        // fold: MT[n][k], bfold
    if (threadIdx.x < 128) {
      int n = threadIdx.x;
      int k = b;
      const float* arow = (k < 64) ? (W_enc + (size_t)k * 128) : b_enc;
      float acc = 0.f;
      for (int j = 0; j < 128; j++)
        acc = fmaf(arow[j], Wc[(size_t)j * 128 + n], acc);
      if (k < 64) ((__half*)MT)[(size_t)n * 64 + k] = __float2half(acc);
      else bfold[n] = acc;
    }
    return;
  }
  b -= 65;
  if (b < 64) {                        // wprep for layer 1
    if (NL > 1) {
      int i = b * 256 + threadIdx.x;   // 16384
      int n = i & 127, k = i >> 7;
      ((__half*)WT1)[(size_t)n * 128 + k] = __float2half(Wc1[i]);
    }
    return;
  }
  // gstart (last block)
  int g = threadIdx.x;
  if (g <= 64) {
    int lo = 0, hi = N;
    while (lo < hi) {
      int mid = (lo + hi) >> 1;
      if (batch[mid] < g) lo = mid + 1;
      else hi = mid;
    }
    gstart[g] = lo;
  }
}

__global__ __launch_bounds__(256) void k_deg(const int* __restrict__ ei, int E,
                                             int* __restrict__ deg) {
  int i = blockIdx.x * 256 + threadIdx.x;
  if (i < E) atomicAdd(&deg[ei[E + i]], 1);   // dst row
}

// ---- 3-kernel exclusive scan over deg[N] -> rowptr ----
__global__ __launch_bounds__(256) void k_scan_a(const int* __restrict__ deg, int N,
                                                int* __restrict__ rowptr,
                                                int* __restrict__ blksum) {
  __shared__ int s[256];
  int t = threadIdx.x;
  int i = blockIdx.x * 256 + t;
  int v = (i < N) ? deg[i] : 0;
  s[t] = v;
  __syncthreads();
  for (int off = 1; off < 256; off <<= 1) {
    int x = (t >= off) ? s[t - off] : 0;
    __syncthreads();
    s[t] += x;
    __syncthreads();
  }
  if (i < N) rowptr[i] = s[t] - v;            // exclusive (partial)
  if (t == 255) blksum[blockIdx.x] = s[255];
}

__global__ __launch_bounds__(256) void k_scan_b(int* __restrict__ blksum, int nb) {
  __shared__ int s[256];
  int t = threadIdx.x;
  int v = (t < nb) ? blksum[t] : 0;
  s[t] = v;
  __syncthreads();
  for (int off = 1; off < 256; off <<= 1) {
    int x = (t >= off) ? s[t - off] : 0;
    __syncthreads();
    s[t] += x;
    __syncthreads();
  }
  if (t < nb) blksum[t] = s[t] - v;           // exclusive
}

__global__ __launch_bounds__(256) void k_scan_c(const int* __restrict__ deg, int N,
                                                int total,
                                                const int* __restrict__ blksum,
                                                int* __restrict__ rowptr,
                                                int* __restrict__ cursor,
                                                float* __restrict__ dinv) {
  int i = blockIdx.x * 256 + threadIdx.x;
  if (i < N) {
    int rp = rowptr[i] + blksum[blockIdx.x];
    rowptr[i] = rp;
    cursor[i] = rp;
    dinv[i] = rsqrtf((float)deg[i]);
  } else if (i == N) {
    rowptr[N] = total;
  }
}

// ---- CSR fill + prep0 (both depend only on scan_c) in one dispatch ----
__global__ __launch_bounds__(256) void k_fillprep(
    const int* __restrict__ ei, int E, int N, int nbEN,
    int* __restrict__ cursor, int* __restrict__ colx,
    const float* __restrict__ x, const float* __restrict__ dinv,
    unsigned* __restrict__ xs2) {
  int b = blockIdx.x;
  if (b < nbEN) {                      // CSR fill
    int i = b * 256 + threadIdx.x;
    if (i < E) {
      int s = ei[i];
      int d = ei[E + i];
      int pos = atomicAdd(&cursor[d], 1);
      colx[pos] = s;
    } else if (i < E + N) {
      int j = i - E;
      int pos = atomicAdd(&cursor[j], 1);
      colx[pos] = j;                   // self-loop entry
    }
    return;
  }
  b -= nbEN;                           // prep0: xs fp16 = x * dinv[row]
  int i = b * 256 + threadIdx.x;
  if (i < N * 16) {
    int row = i >> 4;
    float4 v = ((const float4*)x)[i];
    float d = dinv[row];
    uint2 o;
    o.x = pack2(v.x * d, v.y * d);
    o.y = pack2(v.z * d, v.w * d);
    ((uint2*)xs2)[i] = o;
  }
}

// ---- prep1: hs fp16 = relu(h16*sc+sh)*dinv ; scale/shift computed inline
//      from layer-0 stat replicas (bnfinal fused, R8) ----
__global__ __launch_bounds__(256) void k_prep1(const unsigned short* __restrict__ H16,
                                               const float* __restrict__ stat,
                                               const float* __restrict__ gamma,
                                               const float* __restrict__ beta,
                                               float invN,
                                               const float* __restrict__ dinv,
                                               unsigned* __restrict__ hs2,
                                               int total /* N*32 */) {
  __shared__ float scsh[256];
  if (threadIdx.x < 128) {
    int c = threadIdx.x;
    float ss = 0.f, qs = 0.f;
#pragma unroll
    for (int r = 0; r < 8; r++) {
      ss += stat[r * 256 + c];
      qs += stat[r * 256 + 128 + c];
    }
    float mu = ss * invN;
    float var = qs * invN - mu * mu;
    float sc = rsqrtf(var + 1e-5f) * gamma[c];
    scsh[c] = sc;
    scsh[128 + c] = beta[c] - mu * sc;
  }
  __syncthreads();
  int i = blockIdx.x * 256 + threadIdx.x;
  if (i < total) {
    int row = i >> 5;
    int c4 = i & 31;
    uint2 hv = ((const uint2*)H16)[i];
    float2 h01 = unpack2(hv.x), h23 = unpack2(hv.y);
    float4 sc = *(const float4*)&scsh[c4 * 4];
    float4 sh = *(const float4*)&scsh[128 + c4 * 4];
    float d = dinv[row];
    float a = fmaxf(fmaf(h01.x, sc.x, sh.x), 0.f) * d;
    float b = fmaxf(fmaf(h01.y, sc.y, sh.y), 0.f) * d;
    float c = fmaxf(fmaf(h23.x, sc.z, sh.z), 0.f) * d;
    float e = fmaxf(fmaf(h23.y, sc.w, sh.w), 0.f) * d;
    uint2 o;
    o.x = pack2(a, b);
    o.y = pack2(c, e);
    ((uint2*)hs2)[i] = o;
  }
}

// ---- agg0: quarter-wave per row (16 lanes x uint2 = 128B row, 4 rows/wave) ----
__global__ __launch_bounds__(256) void k_agg0(const uint2* __restrict__ xs,
                                              const int* __restrict__ rowptr,
                                              const int* __restrict__ colx,
                                              const float* __restrict__ dinv,
                                              uint2* __restrict__ axh,
                                              float* __restrict__ w, int N) {
  int lane = threadIdx.x & 63;
  int wv = threadIdx.x >> 6;
  int grp = lane >> 4;           // 0..3: row within wave
  int l16 = lane & 15;
  int wid = blockIdx.x * 4 + wv;
  int nw = gridDim.x * 4;

  for (int base = 4 * wid; base < N; base += 4 * nw) {
    int i = base + grp;
    if (i < N) {
      int beg = rowptr[i];
      int end = rowptr[i + 1];
      float s0 = 0.f, s1 = 0.f, s2 = 0.f, s3 = 0.f, sd = 0.f;
      int e = beg;
#pragma unroll 1
      for (; e + 4 <= end; e += 4) {
        int i0 = colx[e + 0], i1 = colx[e + 1], i2 = colx[e + 2], i3 = colx[e + 3];
        uint2 v0 = xs[(size_t)i0 * 16 + l16];
        uint2 v1 = xs[(size_t)i1 * 16 + l16];
        uint2 v2 = xs[(size_t)i2 * 16 + l16];
        uint2 v3 = xs[(size_t)i3 * 16 + l16];
        float d0 = dinv[i0], d1 = dinv[i1], d2 = dinv[i2], d3 = dinv[i3];
        float2 a0 = unpack2(v0.x), b0 = unpack2(v0.y);
        float2 a1 = unpack2(v1.x), b1 = unpack2(v1.y);
        float2 a2 = unpack2(v2.x), b2 = unpack2(v2.y);
        float2 a3 = unpack2(v3.x), b3 = unpack2(v3.y);
        s0 += (a0.x + a1.x) + (a2.x + a3.x);
        s1 += (a0.y + a1.y) + (a2.y + a3.y);
        s2 += (b0.x + b1.x) + (b2.x + b3.x);
        s3 += (b0.y + b1.y) + (b2.y + b3.y);
        sd += (d0 + d1) + (d2 + d3);
      }
#pragma unroll 1
      for (; e < end; e++) {
        int sr = colx[e];
        uint2 v = xs[(size_t)sr * 16 + l16];
        float2 a = unpack2(v.x), b = unpack2(v.y);
        s0 += a.x; s1 += a.y; s2 += b.x; s3 += b.y;
        sd += dinv[sr];
      }
      float di = dinv[i];
      axh[(size_t)i * 16 + l16] =
          make_uint2(pack2(s0 * di, s1 * di), pack2(s2 * di, s3 * di));
      if (l16 == 0) w[i] = di * sd;
    }
  }
}

// ---- agg1: half-wave per row (32 lanes x uint2 = 256B row) ----
__global__ __launch_bounds__(256) void k_agg1(const uint2* __restrict__ hs,
                                              const int* __restrict__ rowptr,
                                              const int* __restrict__ colx,
                                              const float* __restrict__ dinv,
                                              uint2* __restrict__ a1h, int N) {
  int lane = threadIdx.x & 63;
  int wv = threadIdx.x >> 6;
  int half = lane >> 5;
  int l32 = lane & 31;
  int wid = blockIdx.x * 4 + wv;
  int nw = gridDim.x * 4;

  for (int base = 2 * wid; base < N; base += 2 * nw) {
    int i = base + half;
    if (i < N) {
      int beg = rowptr[i];
      int end = rowptr[i + 1];
      float4 s = make_float4(0.f, 0.f, 0.f, 0.f);
      int e = beg;
#pragma unroll 1
      for (; e + 4 <= end; e += 4) {
        int i0 = colx[e + 0], i1 = colx[e + 1], i2 = colx[e + 2], i3 = colx[e + 3];
        uint2 v0 = hs[(size_t)i0 * 32 + l32];
        uint2 v1 = hs[(size_t)i1 * 32 + l32];
        uint2 v2 = hs[(size_t)i2 * 32 + l32];
        uint2 v3 = hs[(size_t)i3 * 32 + l32];
        float2 a0 = unpack2(v0.x), b0 = unpack2(v0.y);
        float2 a1f = unpack2(v1.x), b1f = unpack2(v1.y);
        float2 a2 = unpack2(v2.x), b2 = unpack2(v2.y);
        float2 a3 = unpack2(v3.x), b3 = unpack2(v3.y);
        s.x += (a0.x + a1f.x) + (a2.x + a3.x);
        s.y += (a0.y + a1f.y) + (a2.y + a3.y);
        s.z += (b0.x + b1f.x) + (b2.x + b3.x);
        s.w += (b0.y + b1f.y) + (b2.y + b3.y);
      }
#pragma unroll 1
      for (; e < end; e++) {
        int sr = colx[e];
        uint2 v = hs[(size_t)sr * 32 + l32];
        float2 a = unpack2(v.x), b = unpack2(v.y);
        s.x += a.x; s.y += a.y; s.z += b.x; s.w += b.y;
      }
      float di = dinv[i];
      a1h[(size_t)i * 32 + l32] =
          make_uint2(pack2(s.x * di, s.y * di), pack2(s.z * di, s.w * di));
    }
  }
}

// ---- standalone W transpose (only used for layers l>=2) ----
__global__ __launch_bounds__(256) void k_wprep(const float* __restrict__ Wsrc,
                                               unsigned short* __restrict__ WT) {
  int i = blockIdx.x * 256 + threadIdx.x;
  int n = i & 127, k = i >> 7;
  ((__half*)WT)[(size_t)n * 128 + k] = __float2half(Wsrc[i]);
}

// ---- MFMA GEMM (R7 structure): Yh = Xh @ WT + bias (+wvec*bias2), stats x8 ----
template <int K>
__global__ __launch_bounds__(256, 2) void k_gemm_f16(
    const unsigned short* __restrict__ Xh,   // N x K fp16
    const unsigned short* __restrict__ WT,   // 128 x K fp16 (n-major)
    const float* __restrict__ bias,          // [128]
    const float* __restrict__ wvec,          // [N] or null (layer0)
    const float* __restrict__ bias2,         // [128] or null (layer0)
    float* __restrict__ stat,                // 8 x [256] replicas
    unsigned short* __restrict__ Yh,         // N x 128 fp16 out
    int N) {
  constexpr int KP = K + 8;
  constexpr int K8 = K / 8;
  __shared__ unsigned short Wl[128 * KP];
  __shared__ float red[4][2][128];

  for (int i = threadIdx.x; i < 128 * K8; i += 256) {
    int r = i / K8, c = i - r * K8;
    *(uint4*)&Wl[r * KP + c * 8] = ((const uint4*)(WT + (size_t)r * K))[c];
  }
  __syncthreads();

  int lane = threadIdx.x & 63;
  int wv = threadIdx.x >> 6;
  int l15 = lane & 15;
  int kg = lane >> 4;
  int tileRow = blockIdx.x * 64 + wv * 16;

  int arow = tileRow + l15;
  if (arow >= N) arow = N - 1;   // clamp; stores/stats guarded below
  const unsigned short* xp = Xh + (size_t)arow * K + kg * 8;
  f16x8 af[K / 32];
#pragma unroll
  for (int j = 0; j < K / 32; j++) af[j] = *(const f16x8*)(xp + j * 32);

  f32x4 acc[8];
#pragma unroll
  for (int t = 0; t < 8; t++) acc[t] = {0.f, 0.f, 0.f, 0.f};

  const unsigned short* wb = &Wl[l15 * KP + kg * 8];
#pragma unroll
  for (int j = 0; j < K / 32; j++) {
#pragma unroll
    for (int t = 0; t < 8; t++) {
      f16x8 bf = *(const f16x8*)(wb + t * 16 * KP + j * 32);
      acc[t] = __builtin_amdgcn_mfma_f32_16x16x32_f16(af[j], bf, acc[t], 0, 0, 0);
    }
  }

  int rbase = tileRow + kg * 4;
  float wrow[4];
#pragma unroll
  for (int r = 0; r < 4; r++)
    wrow[r] = (wvec && rbase + r < N) ? wvec[rbase + r] : 0.f;

#pragma unroll
  for (int t = 0; t < 8; t++) {
    int ch = t * 16 + l15;
    float bb = bias[ch];
    float b2v = bias2 ? bias2[ch] : 0.f;
    float s = 0.f, q = 0.f;
#pragma unroll
    for (int r = 0; r < 4; r++) {
      int row = rbase + r;
      if (row < N) {
        float o = acc[t][r] + bb;
        if (wvec) o = fmaf(wrow[r], b2v, o);
        __half oh = __float2half(o);
        Yh[(size_t)row * 128 + ch] = *(unsigned short*)&oh;
        s += o;
        q += o * o;
      }
    }
    s += __shfl_xor(s, 16); s += __shfl_xor(s, 32);
    q += __shfl_xor(q, 16); q += __shfl_xor(q, 32);
    if (kg == 0) { red[wv][0][ch] = s; red[wv][1][ch] = q; }
  }
  __syncthreads();
  int st = threadIdx.x >> 7, ch2 = threadIdx.x & 127;
  float v = red[0][st][ch2] + red[1][st][ch2] + red[2][st][ch2] + red[3][st][ch2];
  atomicAdd(&stat[(blockIdx.x & 7) * 256 + st * 128 + ch2], v);
}

// ---- Pool: BN(scale/shift computed inline from stat) + ReLU + segment mean ----
__global__ __launch_bounds__(128) void k_pool(const unsigned short* __restrict__ H16,
                                              const float* __restrict__ stat,
                                              const float* __restrict__ gamma,
                                              const float* __restrict__ beta,
                                              float invN,
                                              const int* __restrict__ gstart,
                                              float* __restrict__ pooled) {
  int c = threadIdx.x;
  float ss = 0.f, qs = 0.f;
#pragma unroll
  for (int r = 0; r < 8; r++) {
    ss += stat[r * 256 + c];
    qs += stat[r * 256 + 128 + c];
  }
  float mu = ss * invN;
  float var = qs * invN - mu * mu;
  float sc = rsqrtf(var + 1e-5f) * gamma[c];
  float sh = beta[c] - mu * sc;

  int g = blockIdx.x >> 3;
  int part = blockIdx.x & 7;
  int beg = gstart[g], end = gstart[g + 1];
  int len = end - beg;
  int pbeg = beg + (len * part) / 8;
  int pend = beg + (len * (part + 1)) / 8;
  float s = 0.f;
  for (int r = pbeg; r < pend; r++) {
    float v = __half2float(((const __half*)H16)[(size_t)r * 128 + c]);
    s += fmaxf(fmaf(v, sc, sh), 0.f);
  }
  atomicAdd(&pooled[g * 128 + c], s);
}

// ---- Head MLP ----
__global__ __launch_bounds__(256) void k_mlp(const float* __restrict__ pooled,
                                             const int* __restrict__ gstart,
                                             const float* __restrict__ W1,
                                             const float* __restrict__ b1,
                                             const float* __restrict__ W2,
                                             const float* __restrict__ b2,
                                             float* __restrict__ out) {
  __shared__ float P[64 * 128];
  __shared__ float Z[64 * 64];
  for (int i = threadIdx.x; i < 64 * 128; i += 256) {
    int g = i >> 7;
    int cnt = gstart[g + 1] - gstart[g];
    P[i] = pooled[i] / (float)(cnt > 1 ? cnt : 1);
  }
  __syncthreads();
  for (int i = threadIdx.x; i < 64 * 64; i += 256) {
    int g = i >> 6, m = i & 63;
    float acc = b1[m];
    for (int k = 0; k < 128; k++) acc += P[(g << 7) + k] * W1[k * 64 + m];
    Z[i] = fmaxf(acc, 0.f);
  }
  __syncthreads();
  if (threadIdx.x < 64) {
    int g = threadIdx.x;
    float acc = b2[0];
    for (int m = 0; m < 64; m++) acc += Z[(g << 6) + m] * W2[m];
    out[g] = 1.f / (1.f + expf(-acc));
  }
}

// ---------------------------------------------------------------------------

extern "C" void kernel_launch(void* const* d_in, const int* in_sizes, int n_in,
                              void* d_out, int out_size, void* d_ws, size_t ws_size,
                              hipStream_t stream) {
  const float* x      = (const float*)d_in[0];
  const int*   ei     = (const int*)d_in[1];
  const int*   batch  = (const int*)d_in[2];
  const float* W_enc  = (const float*)d_in[3];
  const float* b_enc  = (const float*)d_in[4];
  const float* Wc     = (const float*)d_in[5];
  const float* bc     = (const float*)d_in[6];
  const float* gamma  = (const float*)d_in[7];
  const float* beta   = (const float*)d_in[8];
  const float* W1     = (const float*)d_in[9];
  const float* b1     = (const float*)d_in[10];
  const float* W2     = (const float*)d_in[11];
  const float* b2     = (const float*)d_in[12];
  float* out = (float*)d_out;

  const int N = in_sizes[2];         // 50000
  const int E = in_sizes[1] / 2;     // 500000
  const int NL = in_sizes[6] / 128;  // 2 layers

  size_t off = 0;
  auto alloc = [&](size_t bytes) {
    void* p = (char*)d_ws + off;
    off += (bytes + 255) & ~(size_t)255;
    return p;
  };
  unsigned short* h16 = (unsigned short*)alloc((size_t)N * 128 * 2);  // h fp16
  int*   deg    = (int*)alloc((size_t)N * 4);
  float* dinv   = (float*)alloc((size_t)N * 4);
  int*   rowptr = (int*)alloc((size_t)(N + 1) * 4);
  int*   cursor = (int*)alloc((size_t)N * 4);
  int*   colx   = (int*)alloc((size_t)(E + N) * 4);
  int*   blksum = (int*)alloc(1024 * 4);
  float* bnstat = (float*)alloc((size_t)NL * 2048 * 4);  // NL x 8 reps x 256
  float* pooled = (float*)alloc(64 * 128 * 4);
  int*   gstart = (int*)alloc(65 * 4);
  unsigned short* MT  = (unsigned short*)alloc(128 * 64 * 2);   // fp16 (W_enc@Wc0)^T
  unsigned short* WT1 = (unsigned short*)alloc(128 * 128 * 2);  // fp16 Wc[l]^T
  float* bfold  = (float*)alloc(128 * 4);
  unsigned* xs  = (unsigned*)alloc((size_t)N * 64 * 2);    // fp16 x*dinv
  unsigned* hs  = (unsigned*)alloc((size_t)N * 128 * 2);   // fp16 BNReLU(h)*dinv
  unsigned* axh = (unsigned*)alloc((size_t)N * 64 * 2);    // fp16 agg0 out
  uint2*    a1h = (uint2*)alloc((size_t)N * 128 * 2);      // fp16 agg1 out
  float* wv     = (float*)alloc((size_t)N * 4);

  int nbN = (N + 255) / 256;
  int nbEN = (E + N + 255) / 256;
  float invN = 1.f / (float)N;

  k_setup<<<nbN + 130, 256, 0, stream>>>(
      deg, pooled, bnstat, NL * 2048, N, nbN, W_enc, b_enc, Wc, MT, bfold, NL,
      Wc + (size_t)128 * 128, WT1, batch, gstart);
  k_deg<<<(E + 255) / 256, 256, 0, stream>>>(ei, E, deg);
  k_scan_a<<<nbN, 256, 0, stream>>>(deg, N, rowptr, blksum);
  k_scan_b<<<1, 256, 0, stream>>>(blksum, nbN);
  k_scan_c<<<(N + 1 + 255) / 256, 256, 0, stream>>>(deg, N, E + N, blksum,
                                                    rowptr, cursor, dinv);
  k_fillprep<<<nbEN + (N * 16 + 255) / 256, 256, 0, stream>>>(
      ei, E, N, nbEN, cursor, colx, x, dinv, xs);

  int tiles = (N + 63) / 64;

  // ---- layer 0 ----
  k_agg0<<<2048, 256, 0, stream>>>((const uint2*)xs, rowptr, colx, dinv,
                                   (uint2*)axh, wv, N);
  k_gemm_f16<64><<<tiles, 256, 0, stream>>>(
      (const unsigned short*)axh, MT, bc, wv, bfold, bnstat, h16, N);

  // ---- layers 1..NL-1 ----
  for (int l = 1; l < NL; l++) {
    if (l > 1)   // WT1 for l==1 was produced by k_setup
      k_wprep<<<64, 256, 0, stream>>>(Wc + (size_t)l * 128 * 128, WT1);
    k_prep1<<<(N * 32 + 255) / 256, 256, 0, stream>>>(
        h16, bnstat + (l - 1) * 2048, gamma + (l - 1) * 128,
        beta + (l - 1) * 128, invN, dinv, hs, N * 32);
    k_agg1<<<2048, 256, 0, stream>>>((const uint2*)hs, rowptr, colx, dinv,
                                     a1h, N);
    k_gemm_f16<128><<<tiles, 256, 0, stream>>>(
        (const unsigned short*)a1h, WT1, bc + l * 128, nullptr, nullptr,
        bnstat + l * 2048, h16, N);
  }

  k_pool<<<64 * 8, 128, 0, stream>>>(h16, bnstat + (NL - 1) * 2048,
                                     gamma + (NL - 1) * 128,
                                     beta + (NL - 1) * 128, invN, gstart,
                                     pooled);
  k_mlp<<<1, 256, 0, stream>>>(pooled, gstart, W1, b1, W2, b2, out);
}